// Round 19
// baseline (842.851 us; speedup 1.0000x reference)
//
#include <hip/hip_runtime.h>
#include <hip/hip_bf16.h>
#include <math.h>

// Problem constants
constexpr int S    = 2048;
constexpr int D    = 1024;
constexpr int NH   = 16;
constexpr int H2   = 32;      // 2*NH half-heads
constexpr int QKD  = 48;      // HD/2 + RD/2
constexpr int QKP  = 56;      // padded LDS k-stride (112B, 16B-aligned rows)
constexpr int FCAP = 128;     // sign-fixup queue capacity per parity buffer
constexpr float SCALE    = 0.14433756729740643f;  // 48^-0.5
constexpr float LAM_INIT = 0.2f;                  // 0.8 - 0.6*exp(0)
constexpr float EPS      = 1e-5f;
constexpr float THETA    = 1e-3f;  // raw-score sign-ambiguity band (err <= ~5e-5)

typedef __attribute__((ext_vector_type(8)))  short bf16x8;
typedef __attribute__((ext_vector_type(16))) float f32x16;

__device__ __forceinline__ int tile_order(int x) {
  return (x & 1) ? (31 - (x >> 1)) : (x >> 1);
}
__device__ __forceinline__ short f2bf(float x) {
  union { float f; unsigned u; } v; v.f = x;
  unsigned r = v.u + 0x7FFFu + ((v.u >> 16) & 1u);   // round-to-nearest-even
  return (short)(r >> 16);
}
__device__ __forceinline__ float bf2f(short b) {
  union { unsigned u; float f; } v; v.u = ((unsigned)(unsigned short)b) << 16;
  return v.f;
}
// D-fragment row pattern for mfma_f32_32x32x16: row=(reg&3)+8*(reg>>2)+4*(lane>>5)
__device__ __forceinline__ int d_rowpat(int r, int lane) {
  return (r & 3) + 8 * (r >> 2) + 4 * ((lane >> 5) & 1);
}
__device__ __forceinline__ f32x16 fzero16() {
  f32x16 z;
#pragma unroll
  for (int i = 0; i < 16; ++i) z[i] = 0.f;
  return z;
}
// A/B fragment from LDS tile [64 pos][QKP] bf16: lane holds pos=(lane&31)+32*sub,
// k = (lane>>5)*8 + 16*ks .. +7
__device__ __forceinline__ bf16x8 frag56(const short* t, int lane, int sub, int ks) {
  return *(const bf16x8*)(t + ((lane & 31) + 32 * sub) * QKP + ((lane >> 5) << 3) + 16 * ks);
}
__device__ __forceinline__ bf16x8 frag72(const short* t, int lane, int sub, int ks) {
  return *(const bf16x8*)(t + ((lane & 31) + 32 * sub) * 72 + ((lane >> 5) << 3) + 16 * ks);
}
// split-bf16 score: D = Ahi*Bhi + Ahi*Blo + Alo*Bhi over K=48 (3 k-steps)
__device__ __forceinline__ f32x16 score_mfma(
    const short* ah, const short* al, const short* bh, const short* bl,
    int lane, int asub, int bsub) {
  f32x16 acc = fzero16();
#pragma unroll
  for (int t = 0; t < 3; ++t) {
    bf16x8 xh = frag56(ah, lane, asub, t);
    bf16x8 yh = frag56(bh, lane, bsub, t);
    bf16x8 xl = frag56(al, lane, asub, t);
    bf16x8 yl = frag56(bl, lane, bsub, t);
    acc = __builtin_amdgcn_mfma_f32_32x32x16_bf16(xh, yh, acc, 0, 0, 0);
    acc = __builtin_amdgcn_mfma_f32_32x32x16_bf16(xh, yl, acc, 0, 0, 0);
    acc = __builtin_amdgcn_mfma_f32_32x32x16_bf16(xl, yh, acc, 0, 0, 0);
  }
  return acc;
}
// single-bf16 score (m/d insensitive; validated rounds 17/18)
__device__ __forceinline__ f32x16 score_mfma1(
    const short* a, const short* b, int lane, int asub, int bsub) {
  f32x16 acc = fzero16();
#pragma unroll
  for (int t = 0; t < 3; ++t)
    acc = __builtin_amdgcn_mfma_f32_32x32x16_bf16(
        frag56(a, lane, asub, t), frag56(b, lane, bsub, t), acc, 0, 0, 0);
  return acc;
}
// stage a 64x48-bf16 tile (global unpadded, 24 u32/row) into LDS (28 u32/row)
__device__ __forceinline__ void stage_tile(const unsigned* __restrict__ g,
                                           unsigned* __restrict__ lds, int tid) {
  for (int i = tid; i < 64 * 24; i += 256) {
    const int r = i / 24, c = i - r * 24;
    lds[r * 28 + c] = g[r * 24 + c];
  }
}
// register-staged variant: 3 uint2 per thread (256 threads x 24B = 64x48 bf16)
__device__ __forceinline__ void ldg_tile3(const unsigned* __restrict__ g,
                                          int tid, uint2 r[3]) {
  const uint2* g2 = (const uint2*)g;
#pragma unroll
  for (int j = 0; j < 3; ++j) r[j] = g2[tid + j * 256];
}
__device__ __forceinline__ void st_tile3(unsigned* __restrict__ lds,
                                         int tid, const uint2 r[3]) {
#pragma unroll
  for (int j = 0; j < 3; ++j) {
    const int e = 2 * (tid + j * 256);
    const int rr = e / 24, cc = e - rr * 24;   // cc even -> pair stays in-row
    *(uint2*)&lds[rr * 28 + cc] = r[j];
  }
}
// 64x64 bf16 tile (row stride ld_u2 uint2s) -> 4 uint2/thread
__device__ __forceinline__ void ldg_t64(const unsigned* __restrict__ g,
                                        int ld_u2, int tid, uint2 r[4]) {
  const uint2* g2 = (const uint2*)g;
#pragma unroll
  for (int j = 0; j < 4; ++j) {
    const int e = tid + j * 256;
    const int row = e >> 4, c4 = e & 15;
    r[j] = g2[(size_t)row * ld_u2 + c4];
  }
}
__device__ __forceinline__ void st_t64(short* __restrict__ lds,
                                       int tid, const uint2 r[4]) {
#pragma unroll
  for (int j = 0; j < 4; ++j) {
    const int e = tid + j * 256;
    const int row = e >> 4, c4 = e & 15;
    *(uint2*)&lds[row * 72 + c4 * 4] = r[j];
  }
}
// V fragments (4 x bf16x8) for one 64-k tile, straight from global vT
__device__ __forceinline__ void ldg_v4(const short* __restrict__ vb,
                                       int lane, int sub, int k0, bf16x8 r[4]) {
  const short* base = vb + ((size_t)((lane & 31) + 32 * sub)) * S + k0 +
                      ((lane >> 5) << 3);
#pragma unroll
  for (int t = 0; t < 4; ++t) r[t] = *(const bf16x8*)(base + 16 * t);
}
__device__ __forceinline__ float signedp(float sv, float mrow, float rrow) {
  const float e = __expf(fabsf(sv) - mrow) * rrow;
  return (sv > 0.f) ? e : ((sv < 0.f) ? -e : 0.f);
}
// exact f32 dot over 48 contiguous floats (row-major q/k rows)
__device__ __forceinline__ float dot48(const float* __restrict__ a,
                                       const float* __restrict__ b) {
  float s = 0.f;
#pragma unroll
  for (int j = 0; j < 12; ++j) {
    float4 x = *(const float4*)&a[4 * j];
    float4 y = *(const float4*)&b[4 * j];
    s += x.x * y.x + x.y * y.y + x.z * y.z + x.w * y.w;
  }
  return s;
}

// ------------------------------------------------ GEMM (f32), 64x128 tiles
__global__ __launch_bounds__(256) void gemm_f32(
    const float* __restrict__ A, const float* __restrict__ B,
    float* __restrict__ C, int M, int K, int N) {
  __shared__ float As[16][64];
  __shared__ float Bs[16][128];
  const int tid = threadIdx.x;
  const int m0 = blockIdx.y * 64, n0 = blockIdx.x * 128;
  const int ty = tid >> 4, tx = tid & 15;
  float acc[4][8] = {};
  for (int k0 = 0; k0 < K; k0 += 16) {
    {
      const int am = tid >> 2;
      const int ak = (tid & 3) * 4;
      float4 a4 = *(const float4*)&A[(size_t)(m0 + am) * K + k0 + ak];
      As[ak + 0][am] = a4.x; As[ak + 1][am] = a4.y;
      As[ak + 2][am] = a4.z; As[ak + 3][am] = a4.w;
    }
#pragma unroll
    for (int it = 0; it < 2; ++it) {
      const int bk = (tid >> 5) + it * 8;
      const int bn = (tid & 31) * 4;
      const int gn = n0 + bn;
      float4 b4 = make_float4(0.f, 0.f, 0.f, 0.f);
      if (gn < N) b4 = *(const float4*)&B[(size_t)(k0 + bk) * N + gn];
      *(float4*)&Bs[bk][bn] = b4;
    }
    __syncthreads();
#pragma unroll
    for (int kk = 0; kk < 16; ++kk) {
      float a[4], b[8];
      *(float4*)&a[0] = *(const float4*)&As[kk][ty * 4];
      *(float4*)&b[0] = *(const float4*)&Bs[kk][tx * 8];
      *(float4*)&b[4] = *(const float4*)&Bs[kk][tx * 8 + 4];
#pragma unroll
      for (int r = 0; r < 4; ++r)
#pragma unroll
        for (int c = 0; c < 8; ++c) acc[r][c] += a[r] * b[c];
    }
    __syncthreads();
  }
#pragma unroll
  for (int r = 0; r < 4; ++r) {
    const int gm = m0 + ty * 4 + r;
#pragma unroll
    for (int c4 = 0; c4 < 2; ++c4) {
      const int gn = n0 + tx * 8 + c4 * 4;
      if (gn < N) {
        float4 v = make_float4(acc[r][c4 * 4], acc[r][c4 * 4 + 1],
                               acc[r][c4 * 4 + 2], acc[r][c4 * 4 + 3]);
        *(float4*)&C[(size_t)gm * N + gn] = v;
      }
    }
  }
}

// ------------------------------------------------------------ row rmsnorm
__global__ __launch_bounds__(256) void rmsnorm_rows(
    const float* __restrict__ in, const float* __restrict__ w,
    float* __restrict__ out, int stride_in, int width) {
  const int row = blockIdx.x;
  const float* x = in + (size_t)row * stride_in;
  float ss = 0.f;
  for (int j = threadIdx.x; j < width; j += 256) { float v = x[j]; ss += v * v; }
  __shared__ float red[256];
  red[threadIdx.x] = ss;
  __syncthreads();
  for (int o = 128; o; o >>= 1) {
    if (threadIdx.x < o) red[threadIdx.x] += red[threadIdx.x + o];
    __syncthreads();
  }
  const float sc = rsqrtf(red[0] / (float)width + EPS);
  for (int j = threadIdx.x; j < width; j += 256)
    out[(size_t)row * width + j] = x[j] * sc * w[j];
}

// ---- assemble q/k with RoPE -> f32 row-major [h2][S][48] + hi/lo bf16 [h2][S][48]
__global__ __launch_bounds__(64) void assemble_qk(
    const float* __restrict__ qp, const float* __restrict__ kv,
    const float* __restrict__ c, const float* __restrict__ freqs,
    float* __restrict__ qfR, float* __restrict__ kfR,
    short* __restrict__ qhi, short* __restrict__ qlo,
    short* __restrict__ khi, short* __restrict__ klo) {
  const int h2 = blockIdx.x, s0 = blockIdx.y * 64;
  const int tid = threadIdx.x, s = s0 + tid;
  const int m = h2 >> 1, e = h2 & 1;
  const int sp = s >> 2;
  float cs[8], sn[8];
  if (sp > 0) {
#pragma unroll
    for (int t = 0; t < 8; ++t) {
      float a = freqs[(sp - 1) * 8 + t];
      cs[t] = cosf(a); sn[t] = sinf(a);
    }
  }
  float v[48], rr[16];
  // ---- q
  {
    const float* qrow = qp + (size_t)s * (NH * 96) + m * 96;
#pragma unroll
    for (int j = 0; j < 32; ++j) v[j] = qrow[e * 32 + j];
#pragma unroll
    for (int j = 0; j < 16; ++j) rr[j] = qrow[64 + e * 16 + j];
    if (sp > 0) {
#pragma unroll
      for (int t = 0; t < 8; ++t) {
        float a = rr[2 * t], b = rr[2 * t + 1];
        rr[2 * t]     = a * cs[t] - b * sn[t];
        rr[2 * t + 1] = a * sn[t] + b * cs[t];
      }
    }
#pragma unroll
    for (int j = 0; j < 16; ++j) v[32 + j] = rr[j];
    float* dst = qfR + ((size_t)h2 * S + s) * 48;
#pragma unroll
    for (int j = 0; j < 12; ++j)
      *(float4*)&dst[4 * j] = make_float4(v[4 * j], v[4 * j + 1], v[4 * j + 2], v[4 * j + 3]);
    unsigned* dh = (unsigned*)(qhi + ((size_t)h2 * S + s) * 48);
    unsigned* dl = (unsigned*)(qlo + ((size_t)h2 * S + s) * 48);
#pragma unroll
    for (int j = 0; j < 24; ++j) {
      const short h0 = f2bf(v[2 * j]),     h1 = f2bf(v[2 * j + 1]);
      const short l0 = f2bf(v[2 * j] - bf2f(h0));
      const short l1 = f2bf(v[2 * j + 1] - bf2f(h1));
      dh[j] = (unsigned)(unsigned short)h0 | ((unsigned)(unsigned short)h1 << 16);
      dl[j] = (unsigned)(unsigned short)l0 | ((unsigned)(unsigned short)l1 << 16);
    }
  }
  // ---- k
  {
    const float* krow = kv + (size_t)s * (NH * 128) + m * 128;
#pragma unroll
    for (int j = 0; j < 32; ++j) v[j] = krow[e * 32 + j];
#pragma unroll
    for (int j = 0; j < 16; ++j) rr[j] = c[(size_t)s * 288 + 256 + e * 16 + j];
    if (sp > 0) {
#pragma unroll
      for (int t = 0; t < 8; ++t) {
        float a = rr[2 * t], b = rr[2 * t + 1];
        rr[2 * t]     = a * cs[t] - b * sn[t];
        rr[2 * t + 1] = a * sn[t] + b * cs[t];
      }
    }
#pragma unroll
    for (int j = 0; j < 16; ++j) v[32 + j] = rr[j];
    float* dst = kfR + ((size_t)h2 * S + s) * 48;
#pragma unroll
    for (int j = 0; j < 12; ++j)
      *(float4*)&dst[4 * j] = make_float4(v[4 * j], v[4 * j + 1], v[4 * j + 2], v[4 * j + 3]);
    unsigned* dh = (unsigned*)(khi + ((size_t)h2 * S + s) * 48);
    unsigned* dl = (unsigned*)(klo + ((size_t)h2 * S + s) * 48);
#pragma unroll
    for (int j = 0; j < 24; ++j) {
      const short h0 = f2bf(v[2 * j]),     h1 = f2bf(v[2 * j + 1]);
      const short l0 = f2bf(v[2 * j] - bf2f(h0));
      const short l1 = f2bf(v[2 * j + 1] - bf2f(h1));
      dh[j] = (unsigned)(unsigned short)h0 | ((unsigned)(unsigned short)h1 << 16);
      dl[j] = (unsigned)(unsigned short)l0 | ((unsigned)(unsigned short)l1 << 16);
    }
  }
}

// ---- V transposed bf16 hi/lo: vT*[h][d(64)][S]
__global__ __launch_bounds__(256) void assemble_v(
    const float* __restrict__ kv, short* __restrict__ vThi,
    short* __restrict__ vTlo) {
  const int h = blockIdx.x, s0 = blockIdx.y * 64;
  const int tid = threadIdx.x;
  __shared__ float t[64][65];
  for (int i = tid; i < 4096; i += 256) {
    const int sl = i >> 6, dd = i & 63;
    t[sl][dd] = kv[(size_t)(s0 + sl) * (NH * 128) + h * 128 + 64 + dd];
  }
  __syncthreads();
  for (int i = tid; i < 4096; i += 256) {
    const int dd = i >> 6, sl = i & 63;
    const float v = t[sl][dd];
    const short hi = f2bf(v);
    vThi[((size_t)(h * 64 + dd)) * S + s0 + sl] = hi;
    vTlo[((size_t)(h * 64 + dd)) * S + s0 + sl] = f2bf(v - bf2f(hi));
  }
}

// ---- Wo transposed split: WoT*[n][k] from Wo[k][n]
__global__ __launch_bounds__(256) void cvt_wo(
    const float* __restrict__ Wo, short* __restrict__ WoThi,
    short* __restrict__ WoTlo) {
  const int k0 = blockIdx.x * 64, n0 = blockIdx.y * 64;
  __shared__ float t[64][65];
  const int tid = threadIdx.x;
  for (int i = tid; i < 4096; i += 256) {
    const int kk = i >> 6, nn = i & 63;
    t[kk][nn] = Wo[(size_t)(k0 + kk) * D + n0 + nn];
  }
  __syncthreads();
  for (int i = tid; i < 4096; i += 256) {
    const int nn = i >> 6, kk = i & 63;
    const float v = t[kk][nn];
    const short hi = f2bf(v);
    WoThi[(size_t)(n0 + nn) * D + k0 + kk] = hi;
    WoTlo[(size_t)(n0 + nn) * D + k0 + kk] = f2bf(v - bf2f(hi));
  }
}

// lam scalar
__global__ __launch_bounds__(64) void compute_lam(
    const float* __restrict__ lk1, const float* __restrict__ lk2,
    const float* __restrict__ lq1, const float* __restrict__ lq2,
    float* __restrict__ lam) {
  const int t = threadIdx.x;
  float p1 = (t < 32) ? lk1[t] * lq1[t] : 0.f;
  float p2 = (t < 32) ? lk2[t] * lq2[t] : 0.f;
  for (int o = 16; o; o >>= 1) {
    p1 += __shfl_down(p1, o);
    p2 += __shfl_down(p2, o);
  }
  if (t == 0) *lam = expf(p1) - expf(p2) + LAM_INIT;
}

// ---- Pass A: per-row max + 1/denom. Single-bf16 scores, double-buffered K,
// ONE barrier per k-iter (st(i+2) into buf[i&1] happens after barrier(i+1),
// which guarantees all warps finished score(i)).
__global__ __launch_bounds__(256) void attn_md(
    const short* __restrict__ qhi, const short* __restrict__ khi,
    float* __restrict__ mOut, float* __restrict__ rdOut) {
  const int tile = tile_order(blockIdx.x), h2 = blockIdx.y;
  const int q0 = tile * 64;
  __shared__ __align__(16) short qh_s[64 * QKP];
  __shared__ __align__(16) short kh_s[2][64 * QKP];
  __shared__ float mpart[2][64], dpart[2][64];
  const int tid = threadIdx.x, lane = tid & 63, w = tid >> 6;
  const int asub = w >> 1, bsub = w & 1;
  stage_tile((const unsigned*)(qhi + ((size_t)h2 * S + q0) * 48), (unsigned*)qh_s, tid);
  uint2 kh_r[3];
  ldg_tile3((const unsigned*)(khi + (size_t)h2 * S * 48), tid, kh_r);
  float m_acc = -1e30f, d_acc = 0.f;
  const int qg = q0 + 32 * bsub + (lane & 31);
  for (int kt = 0; kt <= tile; ++kt) {
    const int k0 = kt * 64;
    short* kb = kh_s[kt & 1];
    st_tile3((unsigned*)kb, tid, kh_r);
    if (kt < tile)
      ldg_tile3((const unsigned*)(khi + ((size_t)h2 * S + k0 + 64) * 48), tid, kh_r);
    __syncthreads();
    f32x16 acc = score_mfma1(kb, qh_s, lane, asub, bsub);
    float av[16];
    float tm = -1e30f;
    if (kt < tile) {
#pragma unroll
      for (int r = 0; r < 16; ++r) { av[r] = fabsf(acc[r] * SCALE); tm = fmaxf(tm, av[r]); }
    } else {
#pragma unroll
      for (int r = 0; r < 16; ++r) {
        const int kg = k0 + 32 * asub + d_rowpat(r, lane);
        av[r] = (kg <= qg) ? fabsf(acc[r] * SCALE) : -1e30f;
        tm = fmaxf(tm, av[r]);
      }
    }
    const float nm = fmaxf(m_acc, tm);
    if (nm > -1e29f) {
      float add = 0.f;
#pragma unroll
      for (int r = 0; r < 16; ++r) add += __expf(av[r] - nm);
      d_acc = d_acc * __expf(m_acc - nm) + add;
      m_acc = nm;
    }
  }
  {
    const float m2 = __shfl_xor(m_acc, 32);
    const float d2 = __shfl_xor(d_acc, 32);
    const float nm = fmaxf(m_acc, m2);
    float dd = 0.f;
    if (nm > -1e29f) dd = d_acc * __expf(m_acc - nm) + d2 * __expf(m2 - nm);
    if ((lane & 32) == 0) {
      mpart[asub][32 * bsub + (lane & 31)] = nm;
      dpart[asub][32 * bsub + (lane & 31)] = dd;
    }
  }
  __syncthreads();
  if (tid < 64) {
    const float ma = mpart[0][tid], mb = mpart[1][tid];
    const float da = dpart[0][tid], db = dpart[1][tid];
    const float mm = fmaxf(ma, mb);
    const float dsum = da * __expf(ma - mm) + db * __expf(mb - mm);
    mOut[h2 * S + q0 + tid] = mm;
    rdOut[h2 * S + q0 + tid] = 1.0f / dsum;
  }
}

// ---- Pass D (partial + fused g): 2 barriers/iter. Sign fixups applied to
// oacc in registers after PV (parity-double-buffered queue; reset of
// fixcnt[par] at stage(i+2) is ordered after all captures at iter i by
// barrier1(i+1)).
__global__ __launch_bounds__(256) void attn_outp(
    const short* __restrict__ qhi, const short* __restrict__ qlo,
    const short* __restrict__ khi, const short* __restrict__ klo,
    const float* __restrict__ qfR, const float* __restrict__ kfR,
    const short* __restrict__ vThi, const short* __restrict__ vTlo,
    const float* __restrict__ mIn, const float* __restrict__ rdIn,
    float* __restrict__ opA0, float* __restrict__ opB0,
    float* __restrict__ opA1, float* __restrict__ opB1,
    float* __restrict__ gp) {
  const int tile = tile_order(blockIdx.x), h2 = blockIdx.y;
  const int chunk = blockIdx.z;
  const int h = h2 >> 1;
  const int q0 = tile * 64;
  __shared__ __align__(16) short qh_s[64 * QKP], ql_s[64 * QKP];
  __shared__ __align__(16) short kh_s[64 * QKP], kl_s[64 * QKP];
  __shared__ __align__(16) short ph_s[64 * 72], pl_s[64 * 72];
  __shared__ float mrow[64], rrow[64];
  __shared__ float gcol[2][64];
  __shared__ int fixq[2][FCAP];
  __shared__ int fixcnt[2];
  const int tid = threadIdx.x, lane = tid & 63, w = tid >> 6;
  const int qsub = w >> 1, sub2 = w & 1;   // sub2: k-cols (scores) / d-cols (PV)
  const short* vbh = vThi + ((size_t)h * 64) * S;
  const short* vbl = vTlo + ((size_t)h * 64) * S;
  const float* qf = qfR + (size_t)h2 * S * 48;
  const float* kf = kfR + (size_t)h2 * S * 48;
  stage_tile((const unsigned*)(qhi + ((size_t)h2 * S + q0) * 48), (unsigned*)qh_s, tid);
  stage_tile((const unsigned*)(qlo + ((size_t)h2 * S + q0) * 48), (unsigned*)ql_s, tid);
  if (tid < 64) {
    mrow[tid] = mIn[h2 * S + q0 + tid];
    rrow[tid] = rdIn[h2 * S + q0 + tid];
  }
  uint2 kh_r[3], kl_r[3];
  bf16x8 vh_r[4], vl_r[4];
  const int kstart = (chunk <= tile) ? chunk : tile;   // safe prefetch base
  ldg_tile3((const unsigned*)(khi + ((size_t)h2 * S + kstart * 64) * 48), tid, kh_r);
  ldg_tile3((const unsigned*)(klo + ((size_t)h2 * S + kstart * 64) * 48), tid, kl_r);
  ldg_v4(vbh, lane, sub2, kstart * 64, vh_r);
  ldg_v4(vbl, lane, sub2, kstart * 64, vl_r);
  f32x16 oacc = fzero16();
  const int colk = 32 * sub2 + (lane & 31);
  for (int kt = chunk; kt <= tile; kt += 2) {
    const int k0 = kt * 64;
    const int par = ((kt - chunk) >> 1) & 1;
    st_tile3((unsigned*)kh_s, tid, kh_r);
    st_tile3((unsigned*)kl_s, tid, kl_r);
    if (tid == 0) fixcnt[par] = 0;
    if (kt + 2 <= tile) {
      ldg_tile3((const unsigned*)(khi + ((size_t)h2 * S + k0 + 128) * 48), tid, kh_r);
      ldg_tile3((const unsigned*)(klo + ((size_t)h2 * S + k0 + 128) * 48), tid, kl_r);
    }
    __syncthreads();   // barrier1: K + fixcnt reset visible; prev PV done
    f32x16 a = score_mfma(qh_s, ql_s, kh_s, kl_s, lane, qsub, sub2);
    // transform -> P tile; column sums; ambiguous signs queued (parity buf)
    const bool dg = (kt == tile);
    const int kg = k0 + colk;
    float colsum = 0.f;
#pragma unroll
    for (int r = 0; r < 16; ++r) {
      const int row = d_rowpat(r, lane) + 32 * qsub;
      float p = 0.f;
      if (!dg || kg <= (q0 + row)) {
        const float s = a[r];
        p = signedp(s * SCALE, mrow[row], rrow[row]);
        if (fabsf(s) < THETA) {
          const int sg = (s > 0.f) ? 1 : ((s < 0.f) ? 2 : 0);
          const int slot = atomicAdd(&fixcnt[par], 1);
          if (slot < FCAP) fixq[par][slot] = (row << 8) | (colk << 2) | sg;
        }
      }
      colsum += p;
      const short ph = f2bf(p);
      ph_s[row * 72 + colk] = ph;
      pl_s[row * 72 + colk] = f2bf(p - bf2f(ph));
    }
    colsum += __shfl_xor(colsum, 32);
    if ((lane & 32) == 0) gcol[qsub][colk] = colsum;
    __syncthreads();   // barrier2: p + queue + gcol visible
    const int cnt = min(fixcnt[par], FCAP);   // captured before any reset
    // g partials (pre-fixup, same semantics as the old attn_g pass)
    if ((h2 & 1) == 0 && tid < 64)
      gp[((size_t)(tile * NH + h)) * S + k0 + tid] = gcol[0][tid] + gcol[1][tid];
    // PV quadrant via MFMA: split P x split V (Ph*Vh + Ph*Vl + Pl*Vh), K=64
#pragma unroll
    for (int t = 0; t < 4; ++t) {
      bf16x8 pa = frag72(ph_s, lane, qsub, t);
      bf16x8 pl = frag72(pl_s, lane, qsub, t);
      oacc = __builtin_amdgcn_mfma_f32_32x32x16_bf16(pa, vh_r[t], oacc, 0, 0, 0);
      oacc = __builtin_amdgcn_mfma_f32_32x32x16_bf16(pa, vl_r[t], oacc, 0, 0, 0);
      oacc = __builtin_amdgcn_mfma_f32_32x32x16_bf16(pl, vh_r[t], oacc, 0, 0, 0);
    }
    // fix-to-oacc: exact f32 sign corrections, no extra barrier
#pragma unroll 1
    for (int i = 0; i < cnt; ++i) {
      const int e = fixq[par][i];
      const int row = (e >> 8) & 63, ck = (e >> 2) & 63, sgc = e & 3;
      if ((row >> 5) != qsub) continue;                 // 2 warps own the row
      if (((lane >> 5) & 1) != ((row >> 2) & 1)) continue;
      const float sgo = (sgc == 1) ? 1.f : ((sgc == 2) ? -1.f : 0.f);
      const float sx = dot48(qf + (size_t)(q0 + row) * 48,
                             kf + (size_t)(k0 + ck) * 48);
      const float sgn = (sx > 0.f) ? 1.f : ((sx < 0.f) ? -1.f : 0.f);
      if (sgn != sgo) {
        const float delta = (sgn - sgo) * __expf(-mrow[row]) * rrow[row];
        const float v = bf2f(vbh[(size_t)colk * S + k0 + ck]) +
                        bf2f(vbl[(size_t)colk * S + k0 + ck]);
        const float dv = delta * v;
        const int rr = (((row & 31) >> 3) << 2) | (row & 3);
#pragma unroll
        for (int r = 0; r < 16; ++r) if (r == rr) oacc[r] += dv;
      }
    }
    if (kt + 2 <= tile) {
      ldg_v4(vbh, lane, sub2, k0 + 128, vh_r);
      ldg_v4(vbl, lane, sub2, k0 + 128, vl_r);
    }
  }
  // write partial output
  float* op = (h2 & 1) ? (chunk ? opB1 : opB0) : (chunk ? opA1 : opA0);
#pragma unroll
  for (int r = 0; r < 16; ++r) {
    const int row = d_rowpat(r, lane) + 32 * qsub;
    op[((size_t)h * S + q0 + row) * 64 + colk] = oacc[r];
  }
}

// ---- g reduce: g[h][k] = (sum_{qt>=k>>6} gp[qt][h][k]) / S
__global__ __launch_bounds__(256) void g_reduce(
    const float* __restrict__ gp, float* __restrict__ g) {
  const int k = blockIdx.x * 256 + threadIdx.x;
  const int h = blockIdx.y;
  const int kt = k >> 6;
  float s = 0.f;
  for (int qt = kt; qt < 32; ++qt) s += gp[((size_t)(qt * NH + h)) * S + k];
  g[h * S + k] = s * (1.0f / (float)S);
}

// ---- Pass C (2-phase chunked scan): gvc[h,k,dd] = prefix_k g[h,j]*v[h,j,dd]
__global__ __launch_bounds__(64) void gvc_scan1(
    const float* __restrict__ g, const short* __restrict__ vThi,
    const short* __restrict__ vTlo, float* __restrict__ gvc,
    float* __restrict__ csum) {
  const int chunk = blockIdx.x, h = blockIdx.y, dd = threadIdx.x;
  const int k0 = chunk * 64;
  const short* vh = vThi + ((size_t)(h * 64 + dd)) * S + k0;
  const short* vl = vTlo + ((size_t)(h * 64 + dd)) * S + k0;
  const float* gr = g + h * S + k0;
  float run = 0.f;
#pragma unroll 8
  for (int k = 0; k < 64; ++k) {
    run += gr[k] * (bf2f(vh[k]) + bf2f(vl[k]));
    gvc[((size_t)(h * S + k0 + k)) * 64 + dd] = run;
  }
  csum[((size_t)h * 32 + chunk) * 64 + dd] = run;
}
__global__ __launch_bounds__(64) void gvc_scan2(
    float* __restrict__ gvc, const float* __restrict__ csum) {
  const int chunk = blockIdx.x + 1, h = blockIdx.y, dd = threadIdx.x;
  float off = 0.f;
  for (int j = 0; j < chunk; ++j) off += csum[((size_t)h * 32 + j) * 64 + dd];
  const int k0 = chunk * 64;
#pragma unroll 8
  for (int k = 0; k < 64; ++k)
    gvc[((size_t)(h * S + k0 + k)) * 64 + dd] += off;
}

// ---- combine: val = (A0+A1) - lam*(B0+B1) + lam*gvc ; rmsnorm ; split-bf16 out
__global__ __launch_bounds__(256) void combine_out(
    const float* __restrict__ opA0, const float* __restrict__ opA1,
    const float* __restrict__ opB0, const float* __restrict__ opB1,
    const float* __restrict__ gvc, const float* __restrict__ lamPtr,
    const float* __restrict__ normW,
    short* __restrict__ nhi, short* __restrict__ nlo) {
  const int h = blockIdx.y, q0 = blockIdx.x * 64;
  const int tid = threadIdx.x, d = tid & 63, wv = tid >> 6;
  const float lam = *lamPtr;
  const float wn = normW[d];
#pragma unroll 4
  for (int i = 0; i < 16; ++i) {
    const int q = q0 + wv + 4 * i;
    const size_t off = ((size_t)h * S + q) * 64 + d;
    float val = (opA0[off] + opA1[off]) - lam * (opB0[off] + opB1[off])
              + lam * gvc[off];
    float ss = val * val;
#pragma unroll
    for (int o = 1; o < 64; o <<= 1) ss += __shfl_xor(ss, o);
    const float sc = rsqrtf(ss * (1.0f / 64.0f) + EPS);
    const float ov = val * sc * wn;
    const short hi = f2bf(ov);
    nhi[(size_t)q * D + h * 64 + d] = hi;
    nlo[(size_t)q * D + h * 64 + d] = f2bf(ov - bf2f(hi));
  }
}

// ---- final projection: out[M=2048][N=1024] = n @ Wo, split-bf16 MFMA, K=1024
__global__ __launch_bounds__(256) void gemm_bf16s(
    const short* __restrict__ Ahi, const short* __restrict__ Alo,
    const short* __restrict__ BThi, const short* __restrict__ BTlo,
    float* __restrict__ C) {
  const int n0 = blockIdx.x * 64, m0 = blockIdx.y * 64;
  __shared__ __align__(16) short ah_s[64 * 72], al_s[64 * 72];
  __shared__ __align__(16) short bh_s[64 * 72], bl_s[64 * 72];
  const int tid = threadIdx.x, lane = tid & 63, w = tid >> 6;
  const int msub = w >> 1, nsub = w & 1;
  uint2 ah_r[4], al_r[4], bh_r[4], bl_r[4];
  ldg_t64((const unsigned*)(Ahi + (size_t)m0 * D), 256, tid, ah_r);
  ldg_t64((const unsigned*)(Alo + (size_t)m0 * D), 256, tid, al_r);
  ldg_t64((const unsigned*)(BThi + (size_t)n0 * D), 256, tid, bh_r);
  ldg_t64((const unsigned*)(BTlo + (size_t)n0 * D), 256, tid, bl_r);
  f32x16 acc = fzero16();
  for (int kc = 0; kc < 16; ++kc) {
    st_t64(ah_s, tid, ah_r); st_t64(al_s, tid, al_r);
    st_t64(bh_s, tid, bh_r); st_t64(bl_s, tid, bl_r);
    if (kc < 15) {
      const int k0 = (kc + 1) * 64;
      ldg_t64((const unsigned*)(Ahi + (size_t)m0 * D + k0), 256, tid, ah_r);
      ldg_t64((const unsigned*)(Alo + (size_t)m0 * D + k0), 256, tid, al_r);
      ldg_t64((const unsigned*)(BThi + (size_t)n0 * D + k0), 256, tid, bh_r);
      ldg_t64((const unsigned*)(BTlo + (size_t)n0 * D + k0), 256, tid, bl_r);
    }
    __syncthreads();
#pragma unroll
    for (int t = 0; t < 4; ++t) {
      bf16x8 xh = frag72(ah_s, lane, msub, t);
      bf16x8 xl = frag72(al_s, lane, msub, t);
      bf16x8 yh = frag72(bh_s, lane, nsub, t);
      bf16x8 yl = frag72(bl_s, lane, nsub, t);
      acc = __builtin_amdgcn_mfma_f32_32x32x16_bf16(xh, yh, acc, 0, 0, 0);
      acc = __builtin_amdgcn_mfma_f32_32x32x16_bf16(xh, yl, acc, 0, 0, 0);
      acc = __builtin_amdgcn_mfma_f32_32x32x16_bf16(xl, yh, acc, 0, 0, 0);
    }
    __syncthreads();
  }
  const int col = 32 * nsub + (lane & 31);
#pragma unroll
  for (int r = 0; r < 16; ++r) {
    const int row = d_rowpat(r, lane) + 32 * msub;
    C[(size_t)(m0 + row) * D + n0 + col] = acc[r];
  }
}

// ----------------------------------------------------------------- launch
extern "C" void kernel_launch(void* const* d_in, const int* in_sizes, int n_in,
                              void* d_out, int out_size, void* d_ws, size_t ws_size,
                              hipStream_t stream) {
  const float* x     = (const float*)d_in[0];
  const float* freqs = (const float*)d_in[2];
  const float* Wkvd  = (const float*)d_in[3];
  const float* Wqd   = (const float*)d_in[4];
  const float* kvnw  = (const float*)d_in[5];
  const float* qnw   = (const float*)d_in[6];
  const float* Wkvup = (const float*)d_in[7];
  const float* Wqup  = (const float*)d_in[8];
  const float* lk1   = (const float*)d_in[9];
  const float* lk2   = (const float*)d_in[10];
  const float* lq1   = (const float*)d_in[11];
  const float* lq2   = (const float*)d_in[12];
  const float* normw = (const float*)d_in[13];
  const float* Wo    = (const float*)d_in[14];
  float* out = (float*)d_out;

  float* ws = (float*)d_ws;
  float* c      = ws;                          // S*288
  float* ckv    = c     + (size_t)S * 288;     // S*256 (opA0 overlay start)
  float* cqr    = ckv   + (size_t)S * 256;     // S*384
  float* cq     = cqr   + (size_t)S * 384;     // S*384
  float* kvbuf  = cq    + (size_t)S * 384;     // S*2048: gvc + opB0
  float* qp     = kvbuf + (size_t)S * 2048;    // S*1536: opA1 + gp overlays
  float* qfR    = qp    + (size_t)S * 1536;    // 32*S*48 f32 row-major
  float* kfR    = qfR   + (size_t)H2 * S * 48;
  short* qhi    = (short*)(kfR + (size_t)H2 * S * 48);   // each 32*S*48 bf16
  short* qlo    = qhi + (size_t)H2 * S * 48;
  short* khi    = qlo + (size_t)H2 * S * 48;
  short* klo    = khi + (size_t)H2 * S * 48;
  short* vThi   = klo + (size_t)H2 * S * 48;   // 16*64*S bf16
  short* vTlo   = vThi + (size_t)NH * 64 * S;
  float* mbuf   = (float*)(vTlo + (size_t)NH * 64 * S);  // 32*S
  float* rdbuf  = mbuf  + (size_t)H2 * S;      // 32*S
  float* gbuf   = rdbuf + (size_t)H2 * S;      // 16*S
  float* lam    = gbuf  + (size_t)NH * S;      // 1
  float* csum   = lam + 1;                     // 16*32*64
  float* opB1   = csum + (size_t)NH * 32 * 64; // 16*S*64
  short* nhi    = (short*)(opB1 + (size_t)NH * S * 64);  // S*1024 bf16
  short* nlo    = nhi + (size_t)S * D;
  short* WoThi  = nlo + (size_t)S * D;         // 1024*1024 bf16
  short* WoTlo  = WoThi + (size_t)D * D;
  // overlays (dead after assemble): gvc/opB0 in kvbuf, opA0 in ckv..cq,
  // opA1 in qp[0:2M), gp in qp[2M:3.14M).
  float* gvc    = kvbuf;
  float* opB0   = kvbuf + (size_t)NH * S * 64;
  float* opA0   = ckv;
  float* opA1   = qp;
  float* gp     = qp + (size_t)NH * S * 64;

  // 0. Wo transpose+split (independent)
  cvt_wo<<<dim3(16, 16), 256, 0, stream>>>(Wo, WoThi, WoTlo);
  // 1. down-projections
  gemm_f32<<<dim3(3, S / 64), 256, 0, stream>>>(x, Wkvd, c, S, D, 288);
  gemm_f32<<<dim3(3, S / 64), 256, 0, stream>>>(x, Wqd, cqr, S, D, 384);
  // 2. rmsnorms
  rmsnorm_rows<<<S, 256, 0, stream>>>(c, kvnw, ckv, 288, 256);
  rmsnorm_rows<<<S, 256, 0, stream>>>(cqr, qnw, cq, 384, 384);
  // 3. up-projections
  gemm_f32<<<dim3(16, S / 64), 256, 0, stream>>>(ckv, Wkvup, kvbuf, S, 256, 2048);
  gemm_f32<<<dim3(12, S / 64), 256, 0, stream>>>(cq, Wqup, qp, S, 384, 1536);
  // 4. assemble heads (RoPE), f32 row-major + hi/lo bf16 views, V^T hi/lo, lam
  assemble_qk<<<dim3(H2, S / 64), 64, 0, stream>>>(qp, kvbuf, c, freqs,
                                                   qfR, kfR, qhi, qlo, khi, klo);
  assemble_v<<<dim3(NH, S / 64), 256, 0, stream>>>(kvbuf, vThi, vTlo);
  compute_lam<<<1, 64, 0, stream>>>(lk1, lk2, lq1, lq2, lam);
  // 5. attention passes (g fused into attn_outp)
  attn_md<<<dim3(32, H2), 256, 0, stream>>>(qhi, khi, mbuf, rdbuf);
  attn_outp<<<dim3(32, H2, 2), 256, 0, stream>>>(qhi, qlo, khi, klo, qfR, kfR,
                                                 vThi, vTlo, mbuf, rdbuf,
                                                 opA0, opB0, opA1, opB1, gp);
  g_reduce<<<dim3(S / 256, NH), 256, 0, stream>>>(gp, gbuf);
  gvc_scan1<<<dim3(32, NH), 64, 0, stream>>>(gbuf, vThi, vTlo, gvc, csum);
  gvc_scan2<<<dim3(31, NH), 64, 0, stream>>>(gvc, csum);
  combine_out<<<dim3(S / 64, NH), 256, 0, stream>>>(opA0, opA1, opB0, opB1,
                                                    gvc, lam, normw, nhi, nlo);
  // 6. output projection (split-bf16 MFMA)
  gemm_bf16s<<<dim3(D / 64, S / 64), 256, 0, stream>>>(nhi, nlo, WoThi, WoTlo, out);
}

// Round 20
// 739.421 us; speedup vs baseline: 1.1399x; 1.1399x over previous
//
#include <hip/hip_runtime.h>
#include <hip/hip_bf16.h>
#include <math.h>

// Problem constants
constexpr int S    = 2048;
constexpr int D    = 1024;
constexpr int NH   = 16;
constexpr int H2   = 32;      // 2*NH half-heads
constexpr int QKD  = 48;      // HD/2 + RD/2
constexpr int QKP  = 56;      // padded LDS k-stride (112B, 16B-aligned rows)
constexpr int FCAP = 256;     // sign-fixup queue capacity (expected ~2/tile)
constexpr float SCALE    = 0.14433756729740643f;  // 48^-0.5
constexpr float LAM_INIT = 0.2f;                  // 0.8 - 0.6*exp(0)
constexpr float EPS      = 1e-5f;
constexpr float THETA    = 1e-3f;  // raw-score sign-ambiguity band (err <= ~5e-5)

typedef __attribute__((ext_vector_type(8)))  short bf16x8;
typedef __attribute__((ext_vector_type(16))) float f32x16;

__device__ __forceinline__ int tile_order(int x) {
  return (x & 1) ? (31 - (x >> 1)) : (x >> 1);
}
__device__ __forceinline__ short f2bf(float x) {
  union { float f; unsigned u; } v; v.f = x;
  unsigned r = v.u + 0x7FFFu + ((v.u >> 16) & 1u);   // round-to-nearest-even
  return (short)(r >> 16);
}
__device__ __forceinline__ float bf2f(short b) {
  union { unsigned u; float f; } v; v.u = ((unsigned)(unsigned short)b) << 16;
  return v.f;
}
// D-fragment row pattern for mfma_f32_32x32x16: row=(reg&3)+8*(reg>>2)+4*(lane>>5)
__device__ __forceinline__ int d_rowpat(int r, int lane) {
  return (r & 3) + 8 * (r >> 2) + 4 * ((lane >> 5) & 1);
}
__device__ __forceinline__ f32x16 fzero16() {
  f32x16 z;
#pragma unroll
  for (int i = 0; i < 16; ++i) z[i] = 0.f;
  return z;
}
// A/B fragment from LDS tile [64 pos][QKP] bf16: lane holds pos=(lane&31)+32*sub,
// k = (lane>>5)*8 + 16*ks .. +7
__device__ __forceinline__ bf16x8 frag56(const short* t, int lane, int sub, int ks) {
  return *(const bf16x8*)(t + ((lane & 31) + 32 * sub) * QKP + ((lane >> 5) << 3) + 16 * ks);
}
__device__ __forceinline__ bf16x8 frag72(const short* t, int lane, int sub, int ks) {
  return *(const bf16x8*)(t + ((lane & 31) + 32 * sub) * 72 + ((lane >> 5) << 3) + 16 * ks);
}
// split-bf16 score: D = Ahi*Bhi + Ahi*Blo + Alo*Bhi over K=48 (3 k-steps)
__device__ __forceinline__ f32x16 score_mfma(
    const short* ah, const short* al, const short* bh, const short* bl,
    int lane, int asub, int bsub) {
  f32x16 acc = fzero16();
#pragma unroll
  for (int t = 0; t < 3; ++t) {
    bf16x8 xh = frag56(ah, lane, asub, t);
    bf16x8 yh = frag56(bh, lane, bsub, t);
    bf16x8 xl = frag56(al, lane, asub, t);
    bf16x8 yl = frag56(bl, lane, bsub, t);
    acc = __builtin_amdgcn_mfma_f32_32x32x16_bf16(xh, yh, acc, 0, 0, 0);
    acc = __builtin_amdgcn_mfma_f32_32x32x16_bf16(xh, yl, acc, 0, 0, 0);
    acc = __builtin_amdgcn_mfma_f32_32x32x16_bf16(xl, yh, acc, 0, 0, 0);
  }
  return acc;
}
// single-bf16 score (m/d insensitive; validated rounds 17/18)
__device__ __forceinline__ f32x16 score_mfma1(
    const short* a, const short* b, int lane, int asub, int bsub) {
  f32x16 acc = fzero16();
#pragma unroll
  for (int t = 0; t < 3; ++t)
    acc = __builtin_amdgcn_mfma_f32_32x32x16_bf16(
        frag56(a, lane, asub, t), frag56(b, lane, bsub, t), acc, 0, 0, 0);
  return acc;
}
// stage a 64x48-bf16 tile (global unpadded, 24 u32/row) into LDS (28 u32/row)
__device__ __forceinline__ void stage_tile(const unsigned* __restrict__ g,
                                           unsigned* __restrict__ lds, int tid) {
  for (int i = tid; i < 64 * 24; i += 256) {
    const int r = i / 24, c = i - r * 24;
    lds[r * 28 + c] = g[r * 24 + c];
  }
}
// register-staged variant: 3 uint2 per thread (256 threads x 24B = 64x48 bf16)
__device__ __forceinline__ void ldg_tile3(const unsigned* __restrict__ g,
                                          int tid, uint2 r[3]) {
  const uint2* g2 = (const uint2*)g;
#pragma unroll
  for (int j = 0; j < 3; ++j) r[j] = g2[tid + j * 256];
}
__device__ __forceinline__ void st_tile3(unsigned* __restrict__ lds,
                                         int tid, const uint2 r[3]) {
#pragma unroll
  for (int j = 0; j < 3; ++j) {
    const int e = 2 * (tid + j * 256);
    const int rr = e / 24, cc = e - rr * 24;   // cc even -> pair stays in-row
    *(uint2*)&lds[rr * 28 + cc] = r[j];
  }
}
// 64x64 bf16 tile (row stride ld_u2 uint2s) -> 4 uint2/thread
__device__ __forceinline__ void ldg_t64(const unsigned* __restrict__ g,
                                        int ld_u2, int tid, uint2 r[4]) {
  const uint2* g2 = (const uint2*)g;
#pragma unroll
  for (int j = 0; j < 4; ++j) {
    const int e = tid + j * 256;
    const int row = e >> 4, c4 = e & 15;
    r[j] = g2[(size_t)row * ld_u2 + c4];
  }
}
__device__ __forceinline__ void st_t64(short* __restrict__ lds,
                                       int tid, const uint2 r[4]) {
#pragma unroll
  for (int j = 0; j < 4; ++j) {
    const int e = tid + j * 256;
    const int row = e >> 4, c4 = e & 15;
    *(uint2*)&lds[row * 72 + c4 * 4] = r[j];
  }
}
// V fragments (4 x bf16x8) for one 64-k tile, straight from global vT
__device__ __forceinline__ void ldg_v4(const short* __restrict__ vb,
                                       int lane, int sub, int k0, bf16x8 r[4]) {
  const short* base = vb + ((size_t)((lane & 31) + 32 * sub)) * S + k0 +
                      ((lane >> 5) << 3);
#pragma unroll
  for (int t = 0; t < 4; ++t) r[t] = *(const bf16x8*)(base + 16 * t);
}
__device__ __forceinline__ float signedp(float sv, float mrow, float rrow) {
  const float e = __expf(fabsf(sv) - mrow) * rrow;
  return (sv > 0.f) ? e : ((sv < 0.f) ? -e : 0.f);
}
// exact f32 dot over 48 contiguous floats (row-major q/k rows)
__device__ __forceinline__ float dot48(const float* __restrict__ a,
                                       const float* __restrict__ b) {
  float s = 0.f;
#pragma unroll
  for (int j = 0; j < 12; ++j) {
    float4 x = *(const float4*)&a[4 * j];
    float4 y = *(const float4*)&b[4 * j];
    s += x.x * y.x + x.y * y.y + x.z * y.z + x.w * y.w;
  }
  return s;
}

// ------------------------------------------------ GEMM (f32), 64x128 tiles
__global__ __launch_bounds__(256) void gemm_f32(
    const float* __restrict__ A, const float* __restrict__ B,
    float* __restrict__ C, int M, int K, int N) {
  __shared__ float As[16][64];
  __shared__ float Bs[16][128];
  const int tid = threadIdx.x;
  const int m0 = blockIdx.y * 64, n0 = blockIdx.x * 128;
  const int ty = tid >> 4, tx = tid & 15;
  float acc[4][8] = {};
  for (int k0 = 0; k0 < K; k0 += 16) {
    {
      const int am = tid >> 2;
      const int ak = (tid & 3) * 4;
      float4 a4 = *(const float4*)&A[(size_t)(m0 + am) * K + k0 + ak];
      As[ak + 0][am] = a4.x; As[ak + 1][am] = a4.y;
      As[ak + 2][am] = a4.z; As[ak + 3][am] = a4.w;
    }
#pragma unroll
    for (int it = 0; it < 2; ++it) {
      const int bk = (tid >> 5) + it * 8;
      const int bn = (tid & 31) * 4;
      const int gn = n0 + bn;
      float4 b4 = make_float4(0.f, 0.f, 0.f, 0.f);
      if (gn < N) b4 = *(const float4*)&B[(size_t)(k0 + bk) * N + gn];
      *(float4*)&Bs[bk][bn] = b4;
    }
    __syncthreads();
#pragma unroll
    for (int kk = 0; kk < 16; ++kk) {
      float a[4], b[8];
      *(float4*)&a[0] = *(const float4*)&As[kk][ty * 4];
      *(float4*)&b[0] = *(const float4*)&Bs[kk][tx * 8];
      *(float4*)&b[4] = *(const float4*)&Bs[kk][tx * 8 + 4];
#pragma unroll
      for (int r = 0; r < 4; ++r)
#pragma unroll
        for (int c = 0; c < 8; ++c) acc[r][c] += a[r] * b[c];
    }
    __syncthreads();
  }
#pragma unroll
  for (int r = 0; r < 4; ++r) {
    const int gm = m0 + ty * 4 + r;
#pragma unroll
    for (int c4 = 0; c4 < 2; ++c4) {
      const int gn = n0 + tx * 8 + c4 * 4;
      if (gn < N) {
        float4 v = make_float4(acc[r][c4 * 4], acc[r][c4 * 4 + 1],
                               acc[r][c4 * 4 + 2], acc[r][c4 * 4 + 3]);
        *(float4*)&C[(size_t)gm * N + gn] = v;
      }
    }
  }
}

// ------------------------------------------------------------ row rmsnorm
__global__ __launch_bounds__(256) void rmsnorm_rows(
    const float* __restrict__ in, const float* __restrict__ w,
    float* __restrict__ out, int stride_in, int width) {
  const int row = blockIdx.x;
  const float* x = in + (size_t)row * stride_in;
  float ss = 0.f;
  for (int j = threadIdx.x; j < width; j += 256) { float v = x[j]; ss += v * v; }
  __shared__ float red[256];
  red[threadIdx.x] = ss;
  __syncthreads();
  for (int o = 128; o; o >>= 1) {
    if (threadIdx.x < o) red[threadIdx.x] += red[threadIdx.x + o];
    __syncthreads();
  }
  const float sc = rsqrtf(red[0] / (float)width + EPS);
  for (int j = threadIdx.x; j < width; j += 256)
    out[(size_t)row * width + j] = x[j] * sc * w[j];
}

// ---- assemble q/k with RoPE -> f32 row-major [h2][S][48] + hi/lo bf16 [h2][S][48]
__global__ __launch_bounds__(64) void assemble_qk(
    const float* __restrict__ qp, const float* __restrict__ kv,
    const float* __restrict__ c, const float* __restrict__ freqs,
    float* __restrict__ qfR, float* __restrict__ kfR,
    short* __restrict__ qhi, short* __restrict__ qlo,
    short* __restrict__ khi, short* __restrict__ klo) {
  const int h2 = blockIdx.x, s0 = blockIdx.y * 64;
  const int tid = threadIdx.x, s = s0 + tid;
  const int m = h2 >> 1, e = h2 & 1;
  const int sp = s >> 2;
  float cs[8], sn[8];
  if (sp > 0) {
#pragma unroll
    for (int t = 0; t < 8; ++t) {
      float a = freqs[(sp - 1) * 8 + t];
      cs[t] = cosf(a); sn[t] = sinf(a);
    }
  }
  float v[48], rr[16];
  // ---- q
  {
    const float* qrow = qp + (size_t)s * (NH * 96) + m * 96;
#pragma unroll
    for (int j = 0; j < 32; ++j) v[j] = qrow[e * 32 + j];
#pragma unroll
    for (int j = 0; j < 16; ++j) rr[j] = qrow[64 + e * 16 + j];
    if (sp > 0) {
#pragma unroll
      for (int t = 0; t < 8; ++t) {
        float a = rr[2 * t], b = rr[2 * t + 1];
        rr[2 * t]     = a * cs[t] - b * sn[t];
        rr[2 * t + 1] = a * sn[t] + b * cs[t];
      }
    }
#pragma unroll
    for (int j = 0; j < 16; ++j) v[32 + j] = rr[j];
    float* dst = qfR + ((size_t)h2 * S + s) * 48;
#pragma unroll
    for (int j = 0; j < 12; ++j)
      *(float4*)&dst[4 * j] = make_float4(v[4 * j], v[4 * j + 1], v[4 * j + 2], v[4 * j + 3]);
    unsigned* dh = (unsigned*)(qhi + ((size_t)h2 * S + s) * 48);
    unsigned* dl = (unsigned*)(qlo + ((size_t)h2 * S + s) * 48);
#pragma unroll
    for (int j = 0; j < 24; ++j) {
      const short h0 = f2bf(v[2 * j]),     h1 = f2bf(v[2 * j + 1]);
      const short l0 = f2bf(v[2 * j] - bf2f(h0));
      const short l1 = f2bf(v[2 * j + 1] - bf2f(h1));
      dh[j] = (unsigned)(unsigned short)h0 | ((unsigned)(unsigned short)h1 << 16);
      dl[j] = (unsigned)(unsigned short)l0 | ((unsigned)(unsigned short)l1 << 16);
    }
  }
  // ---- k
  {
    const float* krow = kv + (size_t)s * (NH * 128) + m * 128;
#pragma unroll
    for (int j = 0; j < 32; ++j) v[j] = krow[e * 32 + j];
#pragma unroll
    for (int j = 0; j < 16; ++j) rr[j] = c[(size_t)s * 288 + 256 + e * 16 + j];
    if (sp > 0) {
#pragma unroll
      for (int t = 0; t < 8; ++t) {
        float a = rr[2 * t], b = rr[2 * t + 1];
        rr[2 * t]     = a * cs[t] - b * sn[t];
        rr[2 * t + 1] = a * sn[t] + b * cs[t];
      }
    }
#pragma unroll
    for (int j = 0; j < 16; ++j) v[32 + j] = rr[j];
    float* dst = kfR + ((size_t)h2 * S + s) * 48;
#pragma unroll
    for (int j = 0; j < 12; ++j)
      *(float4*)&dst[4 * j] = make_float4(v[4 * j], v[4 * j + 1], v[4 * j + 2], v[4 * j + 3]);
    unsigned* dh = (unsigned*)(khi + ((size_t)h2 * S + s) * 48);
    unsigned* dl = (unsigned*)(klo + ((size_t)h2 * S + s) * 48);
#pragma unroll
    for (int j = 0; j < 24; ++j) {
      const short h0 = f2bf(v[2 * j]),     h1 = f2bf(v[2 * j + 1]);
      const short l0 = f2bf(v[2 * j] - bf2f(h0));
      const short l1 = f2bf(v[2 * j + 1] - bf2f(h1));
      dh[j] = (unsigned)(unsigned short)h0 | ((unsigned)(unsigned short)h1 << 16);
      dl[j] = (unsigned)(unsigned short)l0 | ((unsigned)(unsigned short)l1 << 16);
    }
  }
}

// ---- V transposed bf16 hi/lo: vT*[h][d(64)][S]
__global__ __launch_bounds__(256) void assemble_v(
    const float* __restrict__ kv, short* __restrict__ vThi,
    short* __restrict__ vTlo) {
  const int h = blockIdx.x, s0 = blockIdx.y * 64;
  const int tid = threadIdx.x;
  __shared__ float t[64][65];
  for (int i = tid; i < 4096; i += 256) {
    const int sl = i >> 6, dd = i & 63;
    t[sl][dd] = kv[(size_t)(s0 + sl) * (NH * 128) + h * 128 + 64 + dd];
  }
  __syncthreads();
  for (int i = tid; i < 4096; i += 256) {
    const int dd = i >> 6, sl = i & 63;
    const float v = t[sl][dd];
    const short hi = f2bf(v);
    vThi[((size_t)(h * 64 + dd)) * S + s0 + sl] = hi;
    vTlo[((size_t)(h * 64 + dd)) * S + s0 + sl] = f2bf(v - bf2f(hi));
  }
}

// ---- Wo transposed split: WoT*[n][k] from Wo[k][n]
__global__ __launch_bounds__(256) void cvt_wo(
    const float* __restrict__ Wo, short* __restrict__ WoThi,
    short* __restrict__ WoTlo) {
  const int k0 = blockIdx.x * 64, n0 = blockIdx.y * 64;
  __shared__ float t[64][65];
  const int tid = threadIdx.x;
  for (int i = tid; i < 4096; i += 256) {
    const int kk = i >> 6, nn = i & 63;
    t[kk][nn] = Wo[(size_t)(k0 + kk) * D + n0 + nn];
  }
  __syncthreads();
  for (int i = tid; i < 4096; i += 256) {
    const int nn = i >> 6, kk = i & 63;
    const float v = t[kk][nn];
    const short hi = f2bf(v);
    WoThi[(size_t)(n0 + nn) * D + k0 + kk] = hi;
    WoTlo[(size_t)(n0 + nn) * D + k0 + kk] = f2bf(v - bf2f(hi));
  }
}

// lam scalar
__global__ __launch_bounds__(64) void compute_lam(
    const float* __restrict__ lk1, const float* __restrict__ lk2,
    const float* __restrict__ lq1, const float* __restrict__ lq2,
    float* __restrict__ lam) {
  const int t = threadIdx.x;
  float p1 = (t < 32) ? lk1[t] * lq1[t] : 0.f;
  float p2 = (t < 32) ? lk2[t] * lq2[t] : 0.f;
  for (int o = 16; o; o >>= 1) {
    p1 += __shfl_down(p1, o);
    p2 += __shfl_down(p2, o);
  }
  if (t == 0) *lam = expf(p1) - expf(p2) + LAM_INIT;
}

// ---- Pass A: per-row max + 1/denom. Single-bf16 scores (validated r17/r18).
__global__ __launch_bounds__(256) void attn_md(
    const short* __restrict__ qhi, const short* __restrict__ khi,
    float* __restrict__ mOut, float* __restrict__ rdOut) {
  const int tile = tile_order(blockIdx.x), h2 = blockIdx.y;
  const int q0 = tile * 64;
  __shared__ __align__(16) short qh_s[64 * QKP];
  __shared__ __align__(16) short kh_s[64 * QKP];
  __shared__ float mpart[2][64], dpart[2][64];
  const int tid = threadIdx.x, lane = tid & 63, w = tid >> 6;
  const int asub = w >> 1, bsub = w & 1;
  stage_tile((const unsigned*)(qhi + ((size_t)h2 * S + q0) * 48), (unsigned*)qh_s, tid);
  uint2 kh_r[3];
  ldg_tile3((const unsigned*)(khi + (size_t)h2 * S * 48), tid, kh_r);
  float m_acc = -1e30f, d_acc = 0.f;
  const int qg = q0 + 32 * bsub + (lane & 31);
  for (int kt = 0; kt <= tile; ++kt) {
    const int k0 = kt * 64;
    st_tile3((unsigned*)kh_s, tid, kh_r);
    if (kt < tile)
      ldg_tile3((const unsigned*)(khi + ((size_t)h2 * S + k0 + 64) * 48), tid, kh_r);
    __syncthreads();
    f32x16 acc = score_mfma1(kh_s, qh_s, lane, asub, bsub);
    float av[16];
    float tm = -1e30f;
    if (kt < tile) {
#pragma unroll
      for (int r = 0; r < 16; ++r) { av[r] = fabsf(acc[r] * SCALE); tm = fmaxf(tm, av[r]); }
    } else {
#pragma unroll
      for (int r = 0; r < 16; ++r) {
        const int kg = k0 + 32 * asub + d_rowpat(r, lane);
        av[r] = (kg <= qg) ? fabsf(acc[r] * SCALE) : -1e30f;
        tm = fmaxf(tm, av[r]);
      }
    }
    const float nm = fmaxf(m_acc, tm);
    if (nm > -1e29f) {
      float add = 0.f;
#pragma unroll
      for (int r = 0; r < 16; ++r) add += __expf(av[r] - nm);
      d_acc = d_acc * __expf(m_acc - nm) + add;
      m_acc = nm;
    }
    __syncthreads();
  }
  {
    const float m2 = __shfl_xor(m_acc, 32);
    const float d2 = __shfl_xor(d_acc, 32);
    const float nm = fmaxf(m_acc, m2);
    float dd = 0.f;
    if (nm > -1e29f) dd = d_acc * __expf(m_acc - nm) + d2 * __expf(m2 - nm);
    if ((lane & 32) == 0) {
      mpart[asub][32 * bsub + (lane & 31)] = nm;
      dpart[asub][32 * bsub + (lane & 31)] = dd;
    }
  }
  __syncthreads();
  if (tid < 64) {
    const float ma = mpart[0][tid], mb = mpart[1][tid];
    const float da = dpart[0][tid], db = dpart[1][tid];
    const float mm = fmaxf(ma, mb);
    const float dsum = da * __expf(ma - mm) + db * __expf(mb - mm);
    mOut[h2 * S + q0 + tid] = mm;
    rdOut[h2 * S + q0 + tid] = 1.0f / dsum;
  }
}

// ---- Pass D (partial + fused g): one block per (tile, h2), sequential k-loop
// (chunk split removed: r11 vs r13 showed the split cost +40us in-kernel).
__global__ __launch_bounds__(256) void attn_outp(
    const short* __restrict__ qhi, const short* __restrict__ qlo,
    const short* __restrict__ khi, const short* __restrict__ klo,
    const float* __restrict__ qfR, const float* __restrict__ kfR,
    const short* __restrict__ vThi, const short* __restrict__ vTlo,
    const float* __restrict__ mIn, const float* __restrict__ rdIn,
    float* __restrict__ opA0, float* __restrict__ opB0,
    float* __restrict__ gp) {
  const int tile = tile_order(blockIdx.x), h2 = blockIdx.y;
  const int h = h2 >> 1;
  const int q0 = tile * 64;
  __shared__ __align__(16) short qh_s[64 * QKP], ql_s[64 * QKP];
  __shared__ __align__(16) short kh_s[64 * QKP], kl_s[64 * QKP];
  __shared__ __align__(16) short ph_s[64 * 72], pl_s[64 * 72];
  __shared__ float mrow[64], rrow[64];
  __shared__ float gcol[2][64];
  __shared__ int fixq[FCAP];
  __shared__ int fixcnt;
  const int tid = threadIdx.x, lane = tid & 63, w = tid >> 6;
  const int qsub = w >> 1, sub2 = w & 1;   // sub2: k-cols (scores) / d-cols (PV)
  const short* vbh = vThi + ((size_t)h * 64) * S;
  const short* vbl = vTlo + ((size_t)h * 64) * S;
  const float* qf = qfR + (size_t)h2 * S * 48;
  const float* kf = kfR + (size_t)h2 * S * 48;
  stage_tile((const unsigned*)(qhi + ((size_t)h2 * S + q0) * 48), (unsigned*)qh_s, tid);
  stage_tile((const unsigned*)(qlo + ((size_t)h2 * S + q0) * 48), (unsigned*)ql_s, tid);
  if (tid < 64) {
    mrow[tid] = mIn[h2 * S + q0 + tid];
    rrow[tid] = rdIn[h2 * S + q0 + tid];
  }
  uint2 kh_r[3], kl_r[3];
  bf16x8 vh_r[4], vl_r[4];
  ldg_tile3((const unsigned*)(khi + (size_t)h2 * S * 48), tid, kh_r);
  ldg_tile3((const unsigned*)(klo + (size_t)h2 * S * 48), tid, kl_r);
  ldg_v4(vbh, lane, sub2, 0, vh_r);
  ldg_v4(vbl, lane, sub2, 0, vl_r);
  f32x16 oacc = fzero16();
  const int colk = 32 * sub2 + (lane & 31);
  for (int kt = 0; kt <= tile; ++kt) {
    const int k0 = kt * 64;
    st_tile3((unsigned*)kh_s, tid, kh_r);
    st_tile3((unsigned*)kl_s, tid, kl_r);
    if (tid == 0) fixcnt = 0;
    if (kt < tile) {
      ldg_tile3((const unsigned*)(khi + ((size_t)h2 * S + k0 + 64) * 48), tid, kh_r);
      ldg_tile3((const unsigned*)(klo + ((size_t)h2 * S + k0 + 64) * 48), tid, kl_r);
    }
    __syncthreads();   // K ready; prev PV done reading p
    f32x16 a = score_mfma(qh_s, ql_s, kh_s, kl_s, lane, qsub, sub2);
    // transform -> P tile; column sums; ambiguous signs queued
    const bool dg = (kt == tile);
    const int kg = k0 + colk;
    float colsum = 0.f;
#pragma unroll
    for (int r = 0; r < 16; ++r) {
      const int row = d_rowpat(r, lane) + 32 * qsub;
      float p = 0.f;
      if (!dg || kg <= (q0 + row)) {
        const float s = a[r];
        p = signedp(s * SCALE, mrow[row], rrow[row]);
        if (fabsf(s) < THETA) {
          const int sg = (s > 0.f) ? 1 : ((s < 0.f) ? 2 : 0);
          const int slot = atomicAdd(&fixcnt, 1);
          if (slot < FCAP) fixq[slot] = (row << 8) | (colk << 2) | sg;
        }
      }
      colsum += p;
      const short ph = f2bf(p);
      ph_s[row * 72 + colk] = ph;
      pl_s[row * 72 + colk] = f2bf(p - bf2f(ph));
    }
    colsum += __shfl_xor(colsum, 32);
    if ((lane & 32) == 0) gcol[qsub][colk] = colsum;
    __syncthreads();   // p + queue + gcol visible; score reads of kh_s done
    // g partials (pre-fixup, same semantics as the old attn_g pass)
    if ((h2 & 1) == 0 && tid < 64)
      gp[((size_t)(tile * NH + h)) * S + k0 + tid] = gcol[0][tid] + gcol[1][tid];
    if (fixcnt > 0) {  // uniform (LDS value after barrier)
      const int cnt = min(fixcnt, FCAP);
#pragma unroll 1
      for (int i = tid; i < cnt; i += 256) {
        const int e = fixq[i];
        const int row = (e >> 8) & 63, ck = (e >> 2) & 63, sgc = e & 3;
        const float sgo = (sgc == 1) ? 1.f : ((sgc == 2) ? -1.f : 0.f);
        const float sx = dot48(qf + (size_t)(q0 + row) * 48,
                               kf + (size_t)(k0 + ck) * 48);
        const float sgn = (sx > 0.f) ? 1.f : ((sx < 0.f) ? -1.f : 0.f);
        if (sgn != sgo) {
          const float delta = (sgn - sgo) * __expf(-mrow[row]) * rrow[row];
          const int off = row * 72 + ck;
          const float pv = bf2f(ph_s[off]) + bf2f(pl_s[off]) + delta;
          const short nh = f2bf(pv);
          ph_s[off] = nh;
          pl_s[off] = f2bf(pv - bf2f(nh));
        }
      }
      __syncthreads();
    }
    // PV quadrant via MFMA: split P x split V (Ph*Vh + Ph*Vl + Pl*Vh), K=64
#pragma unroll
    for (int t = 0; t < 4; ++t) {
      bf16x8 pa = frag72(ph_s, lane, qsub, t);
      bf16x8 pl = frag72(pl_s, lane, qsub, t);
      oacc = __builtin_amdgcn_mfma_f32_32x32x16_bf16(pa, vh_r[t], oacc, 0, 0, 0);
      oacc = __builtin_amdgcn_mfma_f32_32x32x16_bf16(pa, vl_r[t], oacc, 0, 0, 0);
      oacc = __builtin_amdgcn_mfma_f32_32x32x16_bf16(pl, vh_r[t], oacc, 0, 0, 0);
    }
    if (kt < tile) {
      ldg_v4(vbh, lane, sub2, k0 + 64, vh_r);
      ldg_v4(vbl, lane, sub2, k0 + 64, vl_r);
    }
  }
  // write partial output
  float* op = (h2 & 1) ? opB0 : opA0;
#pragma unroll
  for (int r = 0; r < 16; ++r) {
    const int row = d_rowpat(r, lane) + 32 * qsub;
    op[((size_t)h * S + q0 + row) * 64 + colk] = oacc[r];
  }
}

// ---- g reduce: g[h][k] = (sum_{qt>=k>>6} gp[qt][h][k]) / S
__global__ __launch_bounds__(256) void g_reduce(
    const float* __restrict__ gp, float* __restrict__ g) {
  const int k = blockIdx.x * 256 + threadIdx.x;
  const int h = blockIdx.y;
  const int kt = k >> 6;
  float s = 0.f;
  for (int qt = kt; qt < 32; ++qt) s += gp[((size_t)(qt * NH + h)) * S + k];
  g[h * S + k] = s * (1.0f / (float)S);
}

// ---- Pass C (2-phase chunked scan): gvc[h,k,dd] = prefix_k g[h,j]*v[h,j,dd]
__global__ __launch_bounds__(64) void gvc_scan1(
    const float* __restrict__ g, const short* __restrict__ vThi,
    const short* __restrict__ vTlo, float* __restrict__ gvc,
    float* __restrict__ csum) {
  const int chunk = blockIdx.x, h = blockIdx.y, dd = threadIdx.x;
  const int k0 = chunk * 64;
  const short* vh = vThi + ((size_t)(h * 64 + dd)) * S + k0;
  const short* vl = vTlo + ((size_t)(h * 64 + dd)) * S + k0;
  const float* gr = g + h * S + k0;
  float run = 0.f;
#pragma unroll 8
  for (int k = 0; k < 64; ++k) {
    run += gr[k] * (bf2f(vh[k]) + bf2f(vl[k]));
    gvc[((size_t)(h * S + k0 + k)) * 64 + dd] = run;
  }
  csum[((size_t)h * 32 + chunk) * 64 + dd] = run;
}
__global__ __launch_bounds__(64) void gvc_scan2(
    float* __restrict__ gvc, const float* __restrict__ csum) {
  const int chunk = blockIdx.x + 1, h = blockIdx.y, dd = threadIdx.x;
  float off = 0.f;
  for (int j = 0; j < chunk; ++j) off += csum[((size_t)h * 32 + j) * 64 + dd];
  const int k0 = chunk * 64;
#pragma unroll 8
  for (int k = 0; k < 64; ++k)
    gvc[((size_t)(h * S + k0 + k)) * 64 + dd] += off;
}

// ---- combine: val = opA - lam*opB + lam*gvc ; rmsnorm ; split-bf16 out
__global__ __launch_bounds__(256) void combine_out(
    const float* __restrict__ opA0, const float* __restrict__ opB0,
    const float* __restrict__ gvc, const float* __restrict__ lamPtr,
    const float* __restrict__ normW,
    short* __restrict__ nhi, short* __restrict__ nlo) {
  const int h = blockIdx.y, q0 = blockIdx.x * 64;
  const int tid = threadIdx.x, d = tid & 63, wv = tid >> 6;
  const float lam = *lamPtr;
  const float wn = normW[d];
#pragma unroll 4
  for (int i = 0; i < 16; ++i) {
    const int q = q0 + wv + 4 * i;
    const size_t off = ((size_t)h * S + q) * 64 + d;
    float val = opA0[off] - lam * opB0[off] + lam * gvc[off];
    float ss = val * val;
#pragma unroll
    for (int o = 1; o < 64; o <<= 1) ss += __shfl_xor(ss, o);
    const float sc = rsqrtf(ss * (1.0f / 64.0f) + EPS);
    const float ov = val * sc * wn;
    const short hi = f2bf(ov);
    nhi[(size_t)q * D + h * 64 + d] = hi;
    nlo[(size_t)q * D + h * 64 + d] = f2bf(ov - bf2f(hi));
  }
}

// ---- final projection: out[M=2048][N=1024] = n @ Wo, split-bf16 MFMA, K=1024
__global__ __launch_bounds__(256) void gemm_bf16s(
    const short* __restrict__ Ahi, const short* __restrict__ Alo,
    const short* __restrict__ BThi, const short* __restrict__ BTlo,
    float* __restrict__ C) {
  const int n0 = blockIdx.x * 64, m0 = blockIdx.y * 64;
  __shared__ __align__(16) short ah_s[64 * 72], al_s[64 * 72];
  __shared__ __align__(16) short bh_s[64 * 72], bl_s[64 * 72];
  const int tid = threadIdx.x, lane = tid & 63, w = tid >> 6;
  const int msub = w >> 1, nsub = w & 1;
  uint2 ah_r[4], al_r[4], bh_r[4], bl_r[4];
  ldg_t64((const unsigned*)(Ahi + (size_t)m0 * D), 256, tid, ah_r);
  ldg_t64((const unsigned*)(Alo + (size_t)m0 * D), 256, tid, al_r);
  ldg_t64((const unsigned*)(BThi + (size_t)n0 * D), 256, tid, bh_r);
  ldg_t64((const unsigned*)(BTlo + (size_t)n0 * D), 256, tid, bl_r);
  f32x16 acc = fzero16();
  for (int kc = 0; kc < 16; ++kc) {
    st_t64(ah_s, tid, ah_r); st_t64(al_s, tid, al_r);
    st_t64(bh_s, tid, bh_r); st_t64(bl_s, tid, bl_r);
    if (kc < 15) {
      const int k0 = (kc + 1) * 64;
      ldg_t64((const unsigned*)(Ahi + (size_t)m0 * D + k0), 256, tid, ah_r);
      ldg_t64((const unsigned*)(Alo + (size_t)m0 * D + k0), 256, tid, al_r);
      ldg_t64((const unsigned*)(BThi + (size_t)n0 * D + k0), 256, tid, bh_r);
      ldg_t64((const unsigned*)(BTlo + (size_t)n0 * D + k0), 256, tid, bl_r);
    }
    __syncthreads();
#pragma unroll
    for (int t = 0; t < 4; ++t) {
      bf16x8 xh = frag72(ah_s, lane, msub, t);
      bf16x8 xl = frag72(al_s, lane, msub, t);
      bf16x8 yh = frag72(bh_s, lane, nsub, t);
      bf16x8 yl = frag72(bl_s, lane, nsub, t);
      acc = __builtin_amdgcn_mfma_f32_32x32x16_bf16(xh, yh, acc, 0, 0, 0);
      acc = __builtin_amdgcn_mfma_f32_32x32x16_bf16(xh, yl, acc, 0, 0, 0);
      acc = __builtin_amdgcn_mfma_f32_32x32x16_bf16(xl, yh, acc, 0, 0, 0);
    }
    __syncthreads();
  }
  const int col = 32 * nsub + (lane & 31);
#pragma unroll
  for (int r = 0; r < 16; ++r) {
    const int row = d_rowpat(r, lane) + 32 * msub;
    C[(size_t)(m0 + row) * D + n0 + col] = acc[r];
  }
}

// ----------------------------------------------------------------- launch
extern "C" void kernel_launch(void* const* d_in, const int* in_sizes, int n_in,
                              void* d_out, int out_size, void* d_ws, size_t ws_size,
                              hipStream_t stream) {
  const float* x     = (const float*)d_in[0];
  const float* freqs = (const float*)d_in[2];
  const float* Wkvd  = (const float*)d_in[3];
  const float* Wqd   = (const float*)d_in[4];
  const float* kvnw  = (const float*)d_in[5];
  const float* qnw   = (const float*)d_in[6];
  const float* Wkvup = (const float*)d_in[7];
  const float* Wqup  = (const float*)d_in[8];
  const float* lk1   = (const float*)d_in[9];
  const float* lk2   = (const float*)d_in[10];
  const float* lq1   = (const float*)d_in[11];
  const float* lq2   = (const float*)d_in[12];
  const float* normw = (const float*)d_in[13];
  const float* Wo    = (const float*)d_in[14];
  float* out = (float*)d_out;

  float* ws = (float*)d_ws;
  float* c      = ws;                          // S*288
  float* ckv    = c     + (size_t)S * 288;     // S*256 (opA0 overlay start)
  float* cqr    = ckv   + (size_t)S * 256;     // S*384
  float* cq     = cqr   + (size_t)S * 384;     // S*384
  float* kvbuf  = cq    + (size_t)S * 384;     // S*2048: gvc + opB0
  float* qp     = kvbuf + (size_t)S * 2048;    // S*1536: gp overlay
  float* qfR    = qp    + (size_t)S * 1536;    // 32*S*48 f32 row-major
  float* kfR    = qfR   + (size_t)H2 * S * 48;
  short* qhi    = (short*)(kfR + (size_t)H2 * S * 48);   // each 32*S*48 bf16
  short* qlo    = qhi + (size_t)H2 * S * 48;
  short* khi    = qlo + (size_t)H2 * S * 48;
  short* klo    = khi + (size_t)H2 * S * 48;
  short* vThi   = klo + (size_t)H2 * S * 48;   // 16*64*S bf16
  short* vTlo   = vThi + (size_t)NH * 64 * S;
  float* mbuf   = (float*)(vTlo + (size_t)NH * 64 * S);  // 32*S
  float* rdbuf  = mbuf  + (size_t)H2 * S;      // 32*S
  float* gbuf   = rdbuf + (size_t)H2 * S;      // 16*S
  float* lam    = gbuf  + (size_t)NH * S;      // 1
  float* csum   = lam + 1;                     // 16*32*64
  short* nhi    = (short*)(csum + (size_t)NH * 32 * 64); // S*1024 bf16
  short* nlo    = nhi + (size_t)S * D;
  short* WoThi  = nlo + (size_t)S * D;         // 1024*1024 bf16
  short* WoTlo  = WoThi + (size_t)D * D;
  // overlays (dead after assemble): gvc/opB0 in kvbuf, opA0 in ckv..cq,
  // gp in qp[0:1.05M).
  float* gvc    = kvbuf;
  float* opB0   = kvbuf + (size_t)NH * S * 64;
  float* opA0   = ckv;
  float* gp     = qp;

  // 0. Wo transpose+split (independent)
  cvt_wo<<<dim3(16, 16), 256, 0, stream>>>(Wo, WoThi, WoTlo);
  // 1. down-projections
  gemm_f32<<<dim3(3, S / 64), 256, 0, stream>>>(x, Wkvd, c, S, D, 288);
  gemm_f32<<<dim3(3, S / 64), 256, 0, stream>>>(x, Wqd, cqr, S, D, 384);
  // 2. rmsnorms
  rmsnorm_rows<<<S, 256, 0, stream>>>(c, kvnw, ckv, 288, 256);
  rmsnorm_rows<<<S, 256, 0, stream>>>(cqr, qnw, cq, 384, 384);
  // 3. up-projections
  gemm_f32<<<dim3(16, S / 64), 256, 0, stream>>>(ckv, Wkvup, kvbuf, S, 256, 2048);
  gemm_f32<<<dim3(12, S / 64), 256, 0, stream>>>(cq, Wqup, qp, S, 384, 1536);
  // 4. assemble heads (RoPE), f32 row-major + hi/lo bf16 views, V^T hi/lo, lam
  assemble_qk<<<dim3(H2, S / 64), 64, 0, stream>>>(qp, kvbuf, c, freqs,
                                                   qfR, kfR, qhi, qlo, khi, klo);
  assemble_v<<<dim3(NH, S / 64), 256, 0, stream>>>(kvbuf, vThi, vTlo);
  compute_lam<<<1, 64, 0, stream>>>(lk1, lk2, lq1, lq2, lam);
  // 5. attention passes (g fused into attn_outp)
  attn_md<<<dim3(32, H2), 256, 0, stream>>>(qhi, khi, mbuf, rdbuf);
  attn_outp<<<dim3(32, H2), 256, 0, stream>>>(qhi, qlo, khi, klo, qfR, kfR,
                                              vThi, vTlo, mbuf, rdbuf,
                                              opA0, opB0, gp);
  g_reduce<<<dim3(S / 256, NH), 256, 0, stream>>>(gp, gbuf);
  gvc_scan1<<<dim3(32, NH), 64, 0, stream>>>(gbuf, vThi, vTlo, gvc, csum);
  gvc_scan2<<<dim3(31, NH), 64, 0, stream>>>(gvc, csum);
  combine_out<<<dim3(S / 64, NH), 256, 0, stream>>>(opA0, opB0, gvc, lam,
                                                    normw, nhi, nlo);
  // 6. output projection (split-bf16 MFMA)
  gemm_bf16s<<<dim3(D / 64, S / 64), 256, 0, stream>>>(nhi, nlo, WoThi, WoTlo, out);
}

// Round 21
// 738.958 us; speedup vs baseline: 1.1406x; 1.0006x over previous
//
#include <hip/hip_runtime.h>
#include <hip/hip_bf16.h>
#include <math.h>

// Problem constants
constexpr int S    = 2048;
constexpr int D    = 1024;
constexpr int NH   = 16;
constexpr int H2   = 32;      // 2*NH half-heads
constexpr int QKD  = 48;      // HD/2 + RD/2
constexpr int QKP  = 56;      // padded LDS k-stride (112B, 16B-aligned rows)
constexpr int FCAP = 256;     // sign-fixup queue capacity (expected ~2/tile)
constexpr float SCALE    = 0.14433756729740643f;  // 48^-0.5
constexpr float LAM_INIT = 0.2f;                  // 0.8 - 0.6*exp(0)
constexpr float EPS      = 1e-5f;
constexpr float THETA    = 1e-3f;  // raw-score sign-ambiguity band (err <= ~5e-5)

typedef __attribute__((ext_vector_type(8)))  short bf16x8;
typedef __attribute__((ext_vector_type(16))) float f32x16;

// Relaxed barrier: drain only LDS ops (ds_read/ds_write) of this warp, then
// raw s_barrier. Global loads stay IN FLIGHT across the barrier (unlike
// __syncthreads, which emits s_waitcnt vmcnt(0) and kills register prefetch).
// Safe whenever all cross-warp communication at the barrier is through LDS.
__device__ __forceinline__ void barrier_lds() {
  asm volatile("s_waitcnt lgkmcnt(0)" ::: "memory");
  __builtin_amdgcn_s_barrier();
}

__device__ __forceinline__ int tile_order(int x) {
  return (x & 1) ? (31 - (x >> 1)) : (x >> 1);
}
__device__ __forceinline__ short f2bf(float x) {
  union { float f; unsigned u; } v; v.f = x;
  unsigned r = v.u + 0x7FFFu + ((v.u >> 16) & 1u);   // round-to-nearest-even
  return (short)(r >> 16);
}
__device__ __forceinline__ float bf2f(short b) {
  union { unsigned u; float f; } v; v.u = ((unsigned)(unsigned short)b) << 16;
  return v.f;
}
// D-fragment row pattern for mfma_f32_32x32x16: row=(reg&3)+8*(reg>>2)+4*(lane>>5)
__device__ __forceinline__ int d_rowpat(int r, int lane) {
  return (r & 3) + 8 * (r >> 2) + 4 * ((lane >> 5) & 1);
}
__device__ __forceinline__ f32x16 fzero16() {
  f32x16 z;
#pragma unroll
  for (int i = 0; i < 16; ++i) z[i] = 0.f;
  return z;
}
// A/B fragment from LDS tile [64 pos][QKP] bf16: lane holds pos=(lane&31)+32*sub,
// k = (lane>>5)*8 + 16*ks .. +7
__device__ __forceinline__ bf16x8 frag56(const short* t, int lane, int sub, int ks) {
  return *(const bf16x8*)(t + ((lane & 31) + 32 * sub) * QKP + ((lane >> 5) << 3) + 16 * ks);
}
__device__ __forceinline__ bf16x8 frag72(const short* t, int lane, int sub, int ks) {
  return *(const bf16x8*)(t + ((lane & 31) + 32 * sub) * 72 + ((lane >> 5) << 3) + 16 * ks);
}
// split-bf16 score: D = Ahi*Bhi + Ahi*Blo + Alo*Bhi over K=48 (3 k-steps)
__device__ __forceinline__ f32x16 score_mfma(
    const short* ah, const short* al, const short* bh, const short* bl,
    int lane, int asub, int bsub) {
  f32x16 acc = fzero16();
#pragma unroll
  for (int t = 0; t < 3; ++t) {
    bf16x8 xh = frag56(ah, lane, asub, t);
    bf16x8 yh = frag56(bh, lane, bsub, t);
    bf16x8 xl = frag56(al, lane, asub, t);
    bf16x8 yl = frag56(bl, lane, bsub, t);
    acc = __builtin_amdgcn_mfma_f32_32x32x16_bf16(xh, yh, acc, 0, 0, 0);
    acc = __builtin_amdgcn_mfma_f32_32x32x16_bf16(xh, yl, acc, 0, 0, 0);
    acc = __builtin_amdgcn_mfma_f32_32x32x16_bf16(xl, yh, acc, 0, 0, 0);
  }
  return acc;
}
// single-bf16 score (m/d insensitive; validated rounds 17/18)
__device__ __forceinline__ f32x16 score_mfma1(
    const short* a, const short* b, int lane, int asub, int bsub) {
  f32x16 acc = fzero16();
#pragma unroll
  for (int t = 0; t < 3; ++t)
    acc = __builtin_amdgcn_mfma_f32_32x32x16_bf16(
        frag56(a, lane, asub, t), frag56(b, lane, bsub, t), acc, 0, 0, 0);
  return acc;
}
// stage a 64x48-bf16 tile (global unpadded, 24 u32/row) into LDS (28 u32/row)
__device__ __forceinline__ void stage_tile(const unsigned* __restrict__ g,
                                           unsigned* __restrict__ lds, int tid) {
  for (int i = tid; i < 64 * 24; i += 256) {
    const int r = i / 24, c = i - r * 24;
    lds[r * 28 + c] = g[r * 24 + c];
  }
}
// register-staged variant: 3 uint2 per thread (256 threads x 24B = 64x48 bf16)
__device__ __forceinline__ void ldg_tile3(const unsigned* __restrict__ g,
                                          int tid, uint2 r[3]) {
  const uint2* g2 = (const uint2*)g;
#pragma unroll
  for (int j = 0; j < 3; ++j) r[j] = g2[tid + j * 256];
}
__device__ __forceinline__ void st_tile3(unsigned* __restrict__ lds,
                                         int tid, const uint2 r[3]) {
#pragma unroll
  for (int j = 0; j < 3; ++j) {
    const int e = 2 * (tid + j * 256);
    const int rr = e / 24, cc = e - rr * 24;   // cc even -> pair stays in-row
    *(uint2*)&lds[rr * 28 + cc] = r[j];
  }
}
// 64x64 bf16 tile (row stride ld_u2 uint2s) -> 4 uint2/thread
__device__ __forceinline__ void ldg_t64(const unsigned* __restrict__ g,
                                        int ld_u2, int tid, uint2 r[4]) {
  const uint2* g2 = (const uint2*)g;
#pragma unroll
  for (int j = 0; j < 4; ++j) {
    const int e = tid + j * 256;
    const int row = e >> 4, c4 = e & 15;
    r[j] = g2[(size_t)row * ld_u2 + c4];
  }
}
__device__ __forceinline__ void st_t64(short* __restrict__ lds,
                                       int tid, const uint2 r[4]) {
#pragma unroll
  for (int j = 0; j < 4; ++j) {
    const int e = tid + j * 256;
    const int row = e >> 4, c4 = e & 15;
    *(uint2*)&lds[row * 72 + c4 * 4] = r[j];
  }
}
// V fragments (4 x bf16x8) for one 64-k tile, straight from global vT
__device__ __forceinline__ void ldg_v4(const short* __restrict__ vb,
                                       int lane, int sub, int k0, bf16x8 r[4]) {
  const short* base = vb + ((size_t)((lane & 31) + 32 * sub)) * S + k0 +
                      ((lane >> 5) << 3);
#pragma unroll
  for (int t = 0; t < 4; ++t) r[t] = *(const bf16x8*)(base + 16 * t);
}
__device__ __forceinline__ float signedp(float sv, float mrow, float rrow) {
  const float e = __expf(fabsf(sv) - mrow) * rrow;
  return (sv > 0.f) ? e : ((sv < 0.f) ? -e : 0.f);
}
// exact f32 dot over 48 contiguous floats (row-major q/k rows)
__device__ __forceinline__ float dot48(const float* __restrict__ a,
                                       const float* __restrict__ b) {
  float s = 0.f;
#pragma unroll
  for (int j = 0; j < 12; ++j) {
    float4 x = *(const float4*)&a[4 * j];
    float4 y = *(const float4*)&b[4 * j];
    s += x.x * y.x + x.y * y.y + x.z * y.z + x.w * y.w;
  }
  return s;
}

// ------------------------------------------------ GEMM (f32), 64x128 tiles
__global__ __launch_bounds__(256) void gemm_f32(
    const float* __restrict__ A, const float* __restrict__ B,
    float* __restrict__ C, int M, int K, int N) {
  __shared__ float As[16][64];
  __shared__ float Bs[16][128];
  const int tid = threadIdx.x;
  const int m0 = blockIdx.y * 64, n0 = blockIdx.x * 128;
  const int ty = tid >> 4, tx = tid & 15;
  float acc[4][8] = {};
  for (int k0 = 0; k0 < K; k0 += 16) {
    {
      const int am = tid >> 2;
      const int ak = (tid & 3) * 4;
      float4 a4 = *(const float4*)&A[(size_t)(m0 + am) * K + k0 + ak];
      As[ak + 0][am] = a4.x; As[ak + 1][am] = a4.y;
      As[ak + 2][am] = a4.z; As[ak + 3][am] = a4.w;
    }
#pragma unroll
    for (int it = 0; it < 2; ++it) {
      const int bk = (tid >> 5) + it * 8;
      const int bn = (tid & 31) * 4;
      const int gn = n0 + bn;
      float4 b4 = make_float4(0.f, 0.f, 0.f, 0.f);
      if (gn < N) b4 = *(const float4*)&B[(size_t)(k0 + bk) * N + gn];
      *(float4*)&Bs[bk][bn] = b4;
    }
    __syncthreads();
#pragma unroll
    for (int kk = 0; kk < 16; ++kk) {
      float a[4], b[8];
      *(float4*)&a[0] = *(const float4*)&As[kk][ty * 4];
      *(float4*)&b[0] = *(const float4*)&Bs[kk][tx * 8];
      *(float4*)&b[4] = *(const float4*)&Bs[kk][tx * 8 + 4];
#pragma unroll
      for (int r = 0; r < 4; ++r)
#pragma unroll
        for (int c = 0; c < 8; ++c) acc[r][c] += a[r] * b[c];
    }
    __syncthreads();
  }
#pragma unroll
  for (int r = 0; r < 4; ++r) {
    const int gm = m0 + ty * 4 + r;
#pragma unroll
    for (int c4 = 0; c4 < 2; ++c4) {
      const int gn = n0 + tx * 8 + c4 * 4;
      if (gn < N) {
        float4 v = make_float4(acc[r][c4 * 4], acc[r][c4 * 4 + 1],
                               acc[r][c4 * 4 + 2], acc[r][c4 * 4 + 3]);
        *(float4*)&C[(size_t)gm * N + gn] = v;
      }
    }
  }
}

// ------------------------------------------------------------ row rmsnorm
__global__ __launch_bounds__(256) void rmsnorm_rows(
    const float* __restrict__ in, const float* __restrict__ w,
    float* __restrict__ out, int stride_in, int width) {
  const int row = blockIdx.x;
  const float* x = in + (size_t)row * stride_in;
  float ss = 0.f;
  for (int j = threadIdx.x; j < width; j += 256) { float v = x[j]; ss += v * v; }
  __shared__ float red[256];
  red[threadIdx.x] = ss;
  __syncthreads();
  for (int o = 128; o; o >>= 1) {
    if (threadIdx.x < o) red[threadIdx.x] += red[threadIdx.x + o];
    __syncthreads();
  }
  const float sc = rsqrtf(red[0] / (float)width + EPS);
  for (int j = threadIdx.x; j < width; j += 256)
    out[(size_t)row * width + j] = x[j] * sc * w[j];
}

// ---- assemble q/k with RoPE -> f32 row-major [h2][S][48] + hi/lo bf16 [h2][S][48]
__global__ __launch_bounds__(64) void assemble_qk(
    const float* __restrict__ qp, const float* __restrict__ kv,
    const float* __restrict__ c, const float* __restrict__ freqs,
    float* __restrict__ qfR, float* __restrict__ kfR,
    short* __restrict__ qhi, short* __restrict__ qlo,
    short* __restrict__ khi, short* __restrict__ klo) {
  const int h2 = blockIdx.x, s0 = blockIdx.y * 64;
  const int tid = threadIdx.x, s = s0 + tid;
  const int m = h2 >> 1, e = h2 & 1;
  const int sp = s >> 2;
  float cs[8], sn[8];
  if (sp > 0) {
#pragma unroll
    for (int t = 0; t < 8; ++t) {
      float a = freqs[(sp - 1) * 8 + t];
      cs[t] = cosf(a); sn[t] = sinf(a);
    }
  }
  float v[48], rr[16];
  // ---- q
  {
    const float* qrow = qp + (size_t)s * (NH * 96) + m * 96;
#pragma unroll
    for (int j = 0; j < 32; ++j) v[j] = qrow[e * 32 + j];
#pragma unroll
    for (int j = 0; j < 16; ++j) rr[j] = qrow[64 + e * 16 + j];
    if (sp > 0) {
#pragma unroll
      for (int t = 0; t < 8; ++t) {
        float a = rr[2 * t], b = rr[2 * t + 1];
        rr[2 * t]     = a * cs[t] - b * sn[t];
        rr[2 * t + 1] = a * sn[t] + b * cs[t];
      }
    }
#pragma unroll
    for (int j = 0; j < 16; ++j) v[32 + j] = rr[j];
    float* dst = qfR + ((size_t)h2 * S + s) * 48;
#pragma unroll
    for (int j = 0; j < 12; ++j)
      *(float4*)&dst[4 * j] = make_float4(v[4 * j], v[4 * j + 1], v[4 * j + 2], v[4 * j + 3]);
    unsigned* dh = (unsigned*)(qhi + ((size_t)h2 * S + s) * 48);
    unsigned* dl = (unsigned*)(qlo + ((size_t)h2 * S + s) * 48);
#pragma unroll
    for (int j = 0; j < 24; ++j) {
      const short h0 = f2bf(v[2 * j]),     h1 = f2bf(v[2 * j + 1]);
      const short l0 = f2bf(v[2 * j] - bf2f(h0));
      const short l1 = f2bf(v[2 * j + 1] - bf2f(h1));
      dh[j] = (unsigned)(unsigned short)h0 | ((unsigned)(unsigned short)h1 << 16);
      dl[j] = (unsigned)(unsigned short)l0 | ((unsigned)(unsigned short)l1 << 16);
    }
  }
  // ---- k
  {
    const float* krow = kv + (size_t)s * (NH * 128) + m * 128;
#pragma unroll
    for (int j = 0; j < 32; ++j) v[j] = krow[e * 32 + j];
#pragma unroll
    for (int j = 0; j < 16; ++j) rr[j] = c[(size_t)s * 288 + 256 + e * 16 + j];
    if (sp > 0) {
#pragma unroll
      for (int t = 0; t < 8; ++t) {
        float a = rr[2 * t], b = rr[2 * t + 1];
        rr[2 * t]     = a * cs[t] - b * sn[t];
        rr[2 * t + 1] = a * sn[t] + b * cs[t];
      }
    }
#pragma unroll
    for (int j = 0; j < 16; ++j) v[32 + j] = rr[j];
    float* dst = kfR + ((size_t)h2 * S + s) * 48;
#pragma unroll
    for (int j = 0; j < 12; ++j)
      *(float4*)&dst[4 * j] = make_float4(v[4 * j], v[4 * j + 1], v[4 * j + 2], v[4 * j + 3]);
    unsigned* dh = (unsigned*)(khi + ((size_t)h2 * S + s) * 48);
    unsigned* dl = (unsigned*)(klo + ((size_t)h2 * S + s) * 48);
#pragma unroll
    for (int j = 0; j < 24; ++j) {
      const short h0 = f2bf(v[2 * j]),     h1 = f2bf(v[2 * j + 1]);
      const short l0 = f2bf(v[2 * j] - bf2f(h0));
      const short l1 = f2bf(v[2 * j + 1] - bf2f(h1));
      dh[j] = (unsigned)(unsigned short)h0 | ((unsigned)(unsigned short)h1 << 16);
      dl[j] = (unsigned)(unsigned short)l0 | ((unsigned)(unsigned short)l1 << 16);
    }
  }
}

// ---- V transposed bf16 hi/lo: vT*[h][d(64)][S]
__global__ __launch_bounds__(256) void assemble_v(
    const float* __restrict__ kv, short* __restrict__ vThi,
    short* __restrict__ vTlo) {
  const int h = blockIdx.x, s0 = blockIdx.y * 64;
  const int tid = threadIdx.x;
  __shared__ float t[64][65];
  for (int i = tid; i < 4096; i += 256) {
    const int sl = i >> 6, dd = i & 63;
    t[sl][dd] = kv[(size_t)(s0 + sl) * (NH * 128) + h * 128 + 64 + dd];
  }
  __syncthreads();
  for (int i = tid; i < 4096; i += 256) {
    const int dd = i >> 6, sl = i & 63;
    const float v = t[sl][dd];
    const short hi = f2bf(v);
    vThi[((size_t)(h * 64 + dd)) * S + s0 + sl] = hi;
    vTlo[((size_t)(h * 64 + dd)) * S + s0 + sl] = f2bf(v - bf2f(hi));
  }
}

// ---- Wo transposed split: WoT*[n][k] from Wo[k][n]
__global__ __launch_bounds__(256) void cvt_wo(
    const float* __restrict__ Wo, short* __restrict__ WoThi,
    short* __restrict__ WoTlo) {
  const int k0 = blockIdx.x * 64, n0 = blockIdx.y * 64;
  __shared__ float t[64][65];
  const int tid = threadIdx.x;
  for (int i = tid; i < 4096; i += 256) {
    const int kk = i >> 6, nn = i & 63;
    t[kk][nn] = Wo[(size_t)(k0 + kk) * D + n0 + nn];
  }
  __syncthreads();
  for (int i = tid; i < 4096; i += 256) {
    const int nn = i >> 6, kk = i & 63;
    const float v = t[kk][nn];
    const short hi = f2bf(v);
    WoThi[(size_t)(n0 + nn) * D + k0 + kk] = hi;
    WoTlo[(size_t)(n0 + nn) * D + k0 + kk] = f2bf(v - bf2f(hi));
  }
}

// lam scalar
__global__ __launch_bounds__(64) void compute_lam(
    const float* __restrict__ lk1, const float* __restrict__ lk2,
    const float* __restrict__ lq1, const float* __restrict__ lq2,
    float* __restrict__ lam) {
  const int t = threadIdx.x;
  float p1 = (t < 32) ? lk1[t] * lq1[t] : 0.f;
  float p2 = (t < 32) ? lk2[t] * lq2[t] : 0.f;
  for (int o = 16; o; o >>= 1) {
    p1 += __shfl_down(p1, o);
    p2 += __shfl_down(p2, o);
  }
  if (t == 0) *lam = expf(p1) - expf(p2) + LAM_INIT;
}

// ---- Pass A: per-row max + 1/denom. Single-bf16 scores (validated r17/r18).
// Relaxed in-loop barrier: K prefetch stays in flight across iterations.
__global__ __launch_bounds__(256) void attn_md(
    const short* __restrict__ qhi, const short* __restrict__ khi,
    float* __restrict__ mOut, float* __restrict__ rdOut) {
  const int tile = tile_order(blockIdx.x), h2 = blockIdx.y;
  const int q0 = tile * 64;
  __shared__ __align__(16) short qh_s[64 * QKP];
  __shared__ __align__(16) short kh_s[64 * QKP];
  __shared__ float mpart[2][64], dpart[2][64];
  const int tid = threadIdx.x, lane = tid & 63, w = tid >> 6;
  const int asub = w >> 1, bsub = w & 1;
  stage_tile((const unsigned*)(qhi + ((size_t)h2 * S + q0) * 48), (unsigned*)qh_s, tid);
  uint2 kh_r[3];
  ldg_tile3((const unsigned*)(khi + (size_t)h2 * S * 48), tid, kh_r);
  float m_acc = -1e30f, d_acc = 0.f;
  const int qg = q0 + 32 * bsub + (lane & 31);
  for (int kt = 0; kt <= tile; ++kt) {
    const int k0 = kt * 64;
    st_tile3((unsigned*)kh_s, tid, kh_r);
    if (kt < tile)
      ldg_tile3((const unsigned*)(khi + ((size_t)h2 * S + k0 + 64) * 48), tid, kh_r);
    barrier_lds();
    f32x16 acc = score_mfma1(kh_s, qh_s, lane, asub, bsub);
    float av[16];
    float tm = -1e30f;
    if (kt < tile) {
#pragma unroll
      for (int r = 0; r < 16; ++r) { av[r] = fabsf(acc[r] * SCALE); tm = fmaxf(tm, av[r]); }
    } else {
#pragma unroll
      for (int r = 0; r < 16; ++r) {
        const int kg = k0 + 32 * asub + d_rowpat(r, lane);
        av[r] = (kg <= qg) ? fabsf(acc[r] * SCALE) : -1e30f;
        tm = fmaxf(tm, av[r]);
      }
    }
    const float nm = fmaxf(m_acc, tm);
    if (nm > -1e29f) {
      float add = 0.f;
#pragma unroll
      for (int r = 0; r < 16; ++r) add += __expf(av[r] - nm);
      d_acc = d_acc * __expf(m_acc - nm) + add;
      m_acc = nm;
    }
    barrier_lds();
  }
  {
    const float m2 = __shfl_xor(m_acc, 32);
    const float d2 = __shfl_xor(d_acc, 32);
    const float nm = fmaxf(m_acc, m2);
    float dd = 0.f;
    if (nm > -1e29f) dd = d_acc * __expf(m_acc - nm) + d2 * __expf(m2 - nm);
    if ((lane & 32) == 0) {
      mpart[asub][32 * bsub + (lane & 31)] = nm;
      dpart[asub][32 * bsub + (lane & 31)] = dd;
    }
  }
  __syncthreads();
  if (tid < 64) {
    const float ma = mpart[0][tid], mb = mpart[1][tid];
    const float da = dpart[0][tid], db = dpart[1][tid];
    const float mm = fmaxf(ma, mb);
    const float dsum = da * __expf(ma - mm) + db * __expf(mb - mm);
    mOut[h2 * S + q0 + tid] = mm;
    rdOut[h2 * S + q0 + tid] = 1.0f / dsum;
  }
}

// ---- Pass D (partial + fused g): one block per (tile, h2), sequential k-loop.
// Relaxed in-loop barriers: K/V prefetches stay in flight across barriers.
__global__ __launch_bounds__(256) void attn_outp(
    const short* __restrict__ qhi, const short* __restrict__ qlo,
    const short* __restrict__ khi, const short* __restrict__ klo,
    const float* __restrict__ qfR, const float* __restrict__ kfR,
    const short* __restrict__ vThi, const short* __restrict__ vTlo,
    const float* __restrict__ mIn, const float* __restrict__ rdIn,
    float* __restrict__ opA0, float* __restrict__ opB0,
    float* __restrict__ gp) {
  const int tile = tile_order(blockIdx.x), h2 = blockIdx.y;
  const int h = h2 >> 1;
  const int q0 = tile * 64;
  __shared__ __align__(16) short qh_s[64 * QKP], ql_s[64 * QKP];
  __shared__ __align__(16) short kh_s[64 * QKP], kl_s[64 * QKP];
  __shared__ __align__(16) short ph_s[64 * 72], pl_s[64 * 72];
  __shared__ float mrow[64], rrow[64];
  __shared__ float gcol[2][64];
  __shared__ int fixq[FCAP];
  __shared__ int fixcnt;
  const int tid = threadIdx.x, lane = tid & 63, w = tid >> 6;
  const int qsub = w >> 1, sub2 = w & 1;   // sub2: k-cols (scores) / d-cols (PV)
  const short* vbh = vThi + ((size_t)h * 64) * S;
  const short* vbl = vTlo + ((size_t)h * 64) * S;
  const float* qf = qfR + (size_t)h2 * S * 48;
  const float* kf = kfR + (size_t)h2 * S * 48;
  stage_tile((const unsigned*)(qhi + ((size_t)h2 * S + q0) * 48), (unsigned*)qh_s, tid);
  stage_tile((const unsigned*)(qlo + ((size_t)h2 * S + q0) * 48), (unsigned*)ql_s, tid);
  if (tid < 64) {
    mrow[tid] = mIn[h2 * S + q0 + tid];
    rrow[tid] = rdIn[h2 * S + q0 + tid];
  }
  uint2 kh_r[3], kl_r[3];
  bf16x8 vh_r[4], vl_r[4];
  ldg_tile3((const unsigned*)(khi + (size_t)h2 * S * 48), tid, kh_r);
  ldg_tile3((const unsigned*)(klo + (size_t)h2 * S * 48), tid, kl_r);
  ldg_v4(vbh, lane, sub2, 0, vh_r);
  ldg_v4(vbl, lane, sub2, 0, vl_r);
  f32x16 oacc = fzero16();
  const int colk = 32 * sub2 + (lane & 31);
  for (int kt = 0; kt <= tile; ++kt) {
    const int k0 = kt * 64;
    st_tile3((unsigned*)kh_s, tid, kh_r);
    st_tile3((unsigned*)kl_s, tid, kl_r);
    if (tid == 0) fixcnt = 0;
    if (kt < tile) {
      ldg_tile3((const unsigned*)(khi + ((size_t)h2 * S + k0 + 64) * 48), tid, kh_r);
      ldg_tile3((const unsigned*)(klo + ((size_t)h2 * S + k0 + 64) * 48), tid, kl_r);
    }
    barrier_lds();     // K ready; prev PV done reading p (LDS-only deps)
    f32x16 a = score_mfma(qh_s, ql_s, kh_s, kl_s, lane, qsub, sub2);
    // transform -> P tile; column sums; ambiguous signs queued
    const bool dg = (kt == tile);
    const int kg = k0 + colk;
    float colsum = 0.f;
#pragma unroll
    for (int r = 0; r < 16; ++r) {
      const int row = d_rowpat(r, lane) + 32 * qsub;
      float p = 0.f;
      if (!dg || kg <= (q0 + row)) {
        const float s = a[r];
        p = signedp(s * SCALE, mrow[row], rrow[row]);
        if (fabsf(s) < THETA) {
          const int sg = (s > 0.f) ? 1 : ((s < 0.f) ? 2 : 0);
          const int slot = atomicAdd(&fixcnt, 1);
          if (slot < FCAP) fixq[slot] = (row << 8) | (colk << 2) | sg;
        }
      }
      colsum += p;
      const short ph = f2bf(p);
      ph_s[row * 72 + colk] = ph;
      pl_s[row * 72 + colk] = f2bf(p - bf2f(ph));
    }
    colsum += __shfl_xor(colsum, 32);
    if ((lane & 32) == 0) gcol[qsub][colk] = colsum;
    barrier_lds();     // p + queue + gcol visible (LDS-only deps)
    // g partials (pre-fixup, same semantics as the old attn_g pass)
    if ((h2 & 1) == 0 && tid < 64)
      gp[((size_t)(tile * NH + h)) * S + k0 + tid] = gcol[0][tid] + gcol[1][tid];
    if (fixcnt > 0) {  // uniform (LDS value after barrier)
      const int cnt = min(fixcnt, FCAP);
#pragma unroll 1
      for (int i = tid; i < cnt; i += 256) {
        const int e = fixq[i];
        const int row = (e >> 8) & 63, ck = (e >> 2) & 63, sgc = e & 3;
        const float sgo = (sgc == 1) ? 1.f : ((sgc == 2) ? -1.f : 0.f);
        const float sx = dot48(qf + (size_t)(q0 + row) * 48,
                               kf + (size_t)(k0 + ck) * 48);
        const float sgn = (sx > 0.f) ? 1.f : ((sx < 0.f) ? -1.f : 0.f);
        if (sgn != sgo) {
          const float delta = (sgn - sgo) * __expf(-mrow[row]) * rrow[row];
          const int off = row * 72 + ck;
          const float pv = bf2f(ph_s[off]) + bf2f(pl_s[off]) + delta;
          const short nh = f2bf(pv);
          ph_s[off] = nh;
          pl_s[off] = f2bf(pv - bf2f(nh));
        }
      }
      barrier_lds();
    }
    // PV quadrant via MFMA: split P x split V (Ph*Vh + Ph*Vl + Pl*Vh), K=64
#pragma unroll
    for (int t = 0; t < 4; ++t) {
      bf16x8 pa = frag72(ph_s, lane, qsub, t);
      bf16x8 pl = frag72(pl_s, lane, qsub, t);
      oacc = __builtin_amdgcn_mfma_f32_32x32x16_bf16(pa, vh_r[t], oacc, 0, 0, 0);
      oacc = __builtin_amdgcn_mfma_f32_32x32x16_bf16(pa, vl_r[t], oacc, 0, 0, 0);
      oacc = __builtin_amdgcn_mfma_f32_32x32x16_bf16(pl, vh_r[t], oacc, 0, 0, 0);
    }
    if (kt < tile) {
      ldg_v4(vbh, lane, sub2, k0 + 64, vh_r);
      ldg_v4(vbl, lane, sub2, k0 + 64, vl_r);
    }
  }
  // write partial output
  float* op = (h2 & 1) ? opB0 : opA0;
#pragma unroll
  for (int r = 0; r < 16; ++r) {
    const int row = d_rowpat(r, lane) + 32 * qsub;
    op[((size_t)h * S + q0 + row) * 64 + colk] = oacc[r];
  }
}

// ---- g reduce: g[h][k] = (sum_{qt>=k>>6} gp[qt][h][k]) / S
__global__ __launch_bounds__(256) void g_reduce(
    const float* __restrict__ gp, float* __restrict__ g) {
  const int k = blockIdx.x * 256 + threadIdx.x;
  const int h = blockIdx.y;
  const int kt = k >> 6;
  float s = 0.f;
  for (int qt = kt; qt < 32; ++qt) s += gp[((size_t)(qt * NH + h)) * S + k];
  g[h * S + k] = s * (1.0f / (float)S);
}

// ---- Pass C (2-phase chunked scan): gvc[h,k,dd] = prefix_k g[h,j]*v[h,j,dd]
__global__ __launch_bounds__(64) void gvc_scan1(
    const float* __restrict__ g, const short* __restrict__ vThi,
    const short* __restrict__ vTlo, float* __restrict__ gvc,
    float* __restrict__ csum) {
  const int chunk = blockIdx.x, h = blockIdx.y, dd = threadIdx.x;
  const int k0 = chunk * 64;
  const short* vh = vThi + ((size_t)(h * 64 + dd)) * S + k0;
  const short* vl = vTlo + ((size_t)(h * 64 + dd)) * S + k0;
  const float* gr = g + h * S + k0;
  float run = 0.f;
#pragma unroll 8
  for (int k = 0; k < 64; ++k) {
    run += gr[k] * (bf2f(vh[k]) + bf2f(vl[k]));
    gvc[((size_t)(h * S + k0 + k)) * 64 + dd] = run;
  }
  csum[((size_t)h * 32 + chunk) * 64 + dd] = run;
}
__global__ __launch_bounds__(64) void gvc_scan2(
    float* __restrict__ gvc, const float* __restrict__ csum) {
  const int chunk = blockIdx.x + 1, h = blockIdx.y, dd = threadIdx.x;
  float off = 0.f;
  for (int j = 0; j < chunk; ++j) off += csum[((size_t)h * 32 + j) * 64 + dd];
  const int k0 = chunk * 64;
#pragma unroll 8
  for (int k = 0; k < 64; ++k)
    gvc[((size_t)(h * S + k0 + k)) * 64 + dd] += off;
}

// ---- combine: val = opA - lam*opB + lam*gvc ; rmsnorm ; split-bf16 out
__global__ __launch_bounds__(256) void combine_out(
    const float* __restrict__ opA0, const float* __restrict__ opB0,
    const float* __restrict__ gvc, const float* __restrict__ lamPtr,
    const float* __restrict__ normW,
    short* __restrict__ nhi, short* __restrict__ nlo) {
  const int h = blockIdx.y, q0 = blockIdx.x * 64;
  const int tid = threadIdx.x, d = tid & 63, wv = tid >> 6;
  const float lam = *lamPtr;
  const float wn = normW[d];
#pragma unroll 4
  for (int i = 0; i < 16; ++i) {
    const int q = q0 + wv + 4 * i;
    const size_t off = ((size_t)h * S + q) * 64 + d;
    float val = opA0[off] - lam * opB0[off] + lam * gvc[off];
    float ss = val * val;
#pragma unroll
    for (int o = 1; o < 64; o <<= 1) ss += __shfl_xor(ss, o);
    const float sc = rsqrtf(ss * (1.0f / 64.0f) + EPS);
    const float ov = val * sc * wn;
    const short hi = f2bf(ov);
    nhi[(size_t)q * D + h * 64 + d] = hi;
    nlo[(size_t)q * D + h * 64 + d] = f2bf(ov - bf2f(hi));
  }
}

// ---- final projection: out[M=2048][N=1024] = n @ Wo, split-bf16 MFMA, K=1024
__global__ __launch_bounds__(256) void gemm_bf16s(
    const short* __restrict__ Ahi, const short* __restrict__ Alo,
    const short* __restrict__ BThi, const short* __restrict__ BTlo,
    float* __restrict__ C) {
  const int n0 = blockIdx.x * 64, m0 = blockIdx.y * 64;
  __shared__ __align__(16) short ah_s[64 * 72], al_s[64 * 72];
  __shared__ __align__(16) short bh_s[64 * 72], bl_s[64 * 72];
  const int tid = threadIdx.x, lane = tid & 63, w = tid >> 6;
  const int msub = w >> 1, nsub = w & 1;
  uint2 ah_r[4], al_r[4], bh_r[4], bl_r[4];
  ldg_t64((const unsigned*)(Ahi + (size_t)m0 * D), 256, tid, ah_r);
  ldg_t64((const unsigned*)(Alo + (size_t)m0 * D), 256, tid, al_r);
  ldg_t64((const unsigned*)(BThi + (size_t)n0 * D), 256, tid, bh_r);
  ldg_t64((const unsigned*)(BTlo + (size_t)n0 * D), 256, tid, bl_r);
  f32x16 acc = fzero16();
  for (int kc = 0; kc < 16; ++kc) {
    st_t64(ah_s, tid, ah_r); st_t64(al_s, tid, al_r);
    st_t64(bh_s, tid, bh_r); st_t64(bl_s, tid, bl_r);
    if (kc < 15) {
      const int k0 = (kc + 1) * 64;
      ldg_t64((const unsigned*)(Ahi + (size_t)m0 * D + k0), 256, tid, ah_r);
      ldg_t64((const unsigned*)(Alo + (size_t)m0 * D + k0), 256, tid, al_r);
      ldg_t64((const unsigned*)(BThi + (size_t)n0 * D + k0), 256, tid, bh_r);
      ldg_t64((const unsigned*)(BTlo + (size_t)n0 * D + k0), 256, tid, bl_r);
    }
    barrier_lds();
#pragma unroll
    for (int t = 0; t < 4; ++t) {
      bf16x8 xh = frag72(ah_s, lane, msub, t);
      bf16x8 xl = frag72(al_s, lane, msub, t);
      bf16x8 yh = frag72(bh_s, lane, nsub, t);
      bf16x8 yl = frag72(bl_s, lane, nsub, t);
      acc = __builtin_amdgcn_mfma_f32_32x32x16_bf16(xh, yh, acc, 0, 0, 0);
      acc = __builtin_amdgcn_mfma_f32_32x32x16_bf16(xh, yl, acc, 0, 0, 0);
      acc = __builtin_amdgcn_mfma_f32_32x32x16_bf16(xl, yh, acc, 0, 0, 0);
    }
    barrier_lds();
  }
  const int col = 32 * nsub + (lane & 31);
#pragma unroll
  for (int r = 0; r < 16; ++r) {
    const int row = d_rowpat(r, lane) + 32 * msub;
    C[(size_t)(m0 + row) * D + n0 + col] = acc[r];
  }
}

// ----------------------------------------------------------------- launch
extern "C" void kernel_launch(void* const* d_in, const int* in_sizes, int n_in,
                              void* d_out, int out_size, void* d_ws, size_t ws_size,
                              hipStream_t stream) {
  const float* x     = (const float*)d_in[0];
  const float* freqs = (const float*)d_in[2];
  const float* Wkvd  = (const float*)d_in[3];
  const float* Wqd   = (const float*)d_in[4];
  const float* kvnw  = (const float*)d_in[5];
  const float* qnw   = (const float*)d_in[6];
  const float* Wkvup = (const float*)d_in[7];
  const float* Wqup  = (const float*)d_in[8];
  const float* lk1   = (const float*)d_in[9];
  const float* lk2   = (const float*)d_in[10];
  const float* lq1   = (const float*)d_in[11];
  const float* lq2   = (const float*)d_in[12];
  const float* normw = (const float*)d_in[13];
  const float* Wo    = (const float*)d_in[14];
  float* out = (float*)d_out;

  float* ws = (float*)d_ws;
  float* c      = ws;                          // S*288
  float* ckv    = c     + (size_t)S * 288;     // S*256 (opA0 overlay start)
  float* cqr    = ckv   + (size_t)S * 256;     // S*384
  float* cq     = cqr   + (size_t)S * 384;     // S*384
  float* kvbuf  = cq    + (size_t)S * 384;     // S*2048: gvc + opB0
  float* qp     = kvbuf + (size_t)S * 2048;    // S*1536: gp overlay
  float* qfR    = qp    + (size_t)S * 1536;    // 32*S*48 f32 row-major
  float* kfR    = qfR   + (size_t)H2 * S * 48;
  short* qhi    = (short*)(kfR + (size_t)H2 * S * 48);   // each 32*S*48 bf16
  short* qlo    = qhi + (size_t)H2 * S * 48;
  short* khi    = qlo + (size_t)H2 * S * 48;
  short* klo    = khi + (size_t)H2 * S * 48;
  short* vThi   = klo + (size_t)H2 * S * 48;   // 16*64*S bf16
  short* vTlo   = vThi + (size_t)NH * 64 * S;
  float* mbuf   = (float*)(vTlo + (size_t)NH * 64 * S);  // 32*S
  float* rdbuf  = mbuf  + (size_t)H2 * S;      // 32*S
  float* gbuf   = rdbuf + (size_t)H2 * S;      // 16*S
  float* lam    = gbuf  + (size_t)NH * S;      // 1
  float* csum   = lam + 1;                     // 16*32*64
  short* nhi    = (short*)(csum + (size_t)NH * 32 * 64); // S*1024 bf16
  short* nlo    = nhi + (size_t)S * D;
  short* WoThi  = nlo + (size_t)S * D;         // 1024*1024 bf16
  short* WoTlo  = WoThi + (size_t)D * D;
  // overlays (dead after assemble): gvc/opB0 in kvbuf, opA0 in ckv..cq,
  // gp in qp[0:1.05M).
  float* gvc    = kvbuf;
  float* opB0   = kvbuf + (size_t)NH * S * 64;
  float* opA0   = ckv;
  float* gp     = qp;

  // 0. Wo transpose+split (independent)
  cvt_wo<<<dim3(16, 16), 256, 0, stream>>>(Wo, WoThi, WoTlo);
  // 1. down-projections
  gemm_f32<<<dim3(3, S / 64), 256, 0, stream>>>(x, Wkvd, c, S, D, 288);
  gemm_f32<<<dim3(3, S / 64), 256, 0, stream>>>(x, Wqd, cqr, S, D, 384);
  // 2. rmsnorms
  rmsnorm_rows<<<S, 256, 0, stream>>>(c, kvnw, ckv, 288, 256);
  rmsnorm_rows<<<S, 256, 0, stream>>>(cqr, qnw, cq, 384, 384);
  // 3. up-projections
  gemm_f32<<<dim3(16, S / 64), 256, 0, stream>>>(ckv, Wkvup, kvbuf, S, 256, 2048);
  gemm_f32<<<dim3(12, S / 64), 256, 0, stream>>>(cq, Wqup, qp, S, 384, 1536);
  // 4. assemble heads (RoPE), f32 row-major + hi/lo bf16 views, V^T hi/lo, lam
  assemble_qk<<<dim3(H2, S / 64), 64, 0, stream>>>(qp, kvbuf, c, freqs,
                                                   qfR, kfR, qhi, qlo, khi, klo);
  assemble_v<<<dim3(NH, S / 64), 256, 0, stream>>>(kvbuf, vThi, vTlo);
  compute_lam<<<1, 64, 0, stream>>>(lk1, lk2, lq1, lq2, lam);
  // 5. attention passes (g fused into attn_outp)
  attn_md<<<dim3(32, H2), 256, 0, stream>>>(qhi, khi, mbuf, rdbuf);
  attn_outp<<<dim3(32, H2), 256, 0, stream>>>(qhi, qlo, khi, klo, qfR, kfR,
                                              vThi, vTlo, mbuf, rdbuf,
                                              opA0, opB0, gp);
  g_reduce<<<dim3(S / 256, NH), 256, 0, stream>>>(gp, gbuf);
  gvc_scan1<<<dim3(32, NH), 64, 0, stream>>>(gbuf, vThi, vTlo, gvc, csum);
  gvc_scan2<<<dim3(31, NH), 64, 0, stream>>>(gvc, csum);
  combine_out<<<dim3(S / 64, NH), 256, 0, stream>>>(opA0, opB0, gvc, lam,
                                                    normw, nhi, nlo);
  // 6. output projection (split-bf16 MFMA)
  gemm_bf16s<<<dim3(D / 64, S / 64), 256, 0, stream>>>(nhi, nlo, WoThi, WoTlo, out);
}